// Round 7
// baseline (96258.551 us; speedup 1.0000x reference)
//
#include <hip/hip_runtime.h>
#include <hip/hip_bf16.h>
#include <stdint.h>

typedef __attribute__((ext_vector_type(8))) short short8;
typedef __attribute__((ext_vector_type(4))) float f32x4;

__device__ __forceinline__ unsigned short f2bf(float f) {
  union { float f; unsigned u; } v; v.f = f;
  unsigned r = v.u + 0x7FFFu + ((v.u >> 16) & 1u);
  return (unsigned short)(r >> 16);
}
__device__ __forceinline__ float bf2f(unsigned short h) {
  union { unsigned u; float f; } v; v.u = ((unsigned)h) << 16;
  return v.f;
}
__device__ __forceinline__ float sigm(float x) {
  x = fminf(fmaxf(x, -30.f), 30.f);
  return 1.f / (1.f + __expf(-x));
}
__device__ __forceinline__ float tanh_(float x) {
  x = fminf(fmaxf(x, -15.f), 15.f);
  float t = __expf(2.f * x);
  return (t - 1.f) / (t + 1.f);
}
__device__ __forceinline__ short8 pack8(float4 u, float4 v) {
  short8 r;
  r[0] = (short)f2bf(u.x); r[1] = (short)f2bf(u.y); r[2] = (short)f2bf(u.z); r[3] = (short)f2bf(u.w);
  r[4] = (short)f2bf(v.x); r[5] = (short)f2bf(v.y); r[6] = (short)f2bf(v.z); r[7] = (short)f2bf(v.w);
  return r;
}
// Pack 8 f32 (pre-scaled) into 8 e4m3 bytes (one u64).
__device__ __forceinline__ unsigned long long pack_fp8x8(float4 u, float4 v, float scale) {
  int lo = 0, hi = 0;
  lo = __builtin_amdgcn_cvt_pk_fp8_f32(u.x * scale, u.y * scale, lo, false);
  lo = __builtin_amdgcn_cvt_pk_fp8_f32(u.z * scale, u.w * scale, lo, true);
  hi = __builtin_amdgcn_cvt_pk_fp8_f32(v.x * scale, v.y * scale, hi, false);
  hi = __builtin_amdgcn_cvt_pk_fp8_f32(v.z * scale, v.w * scale, hi, true);
  return ((unsigned long long)(unsigned)lo) | (((unsigned long long)(unsigned)hi) << 32);
}

// bf16 MFMA with B pinned to AGPRs.
#define MFMA_AB(acc, a, b) \
  asm("v_mfma_f32_16x16x32_bf16 %0, %1, %2, %0" : "+v"(acc) : "v"(a), "a"(b))
// fp8 MFMA: acc in VGPR; B from AGPR (persistent weights) or VGPR (LDS-staged).
#define MFMA8_WA(acc, a, b) \
  asm("v_mfma_f32_16x16x32_fp8_fp8 %0, %1, %2, %0" : "+v"(acc) : "v"(a), "a"(b))
#define MFMA8_WV(acc, a, b) \
  asm("v_mfma_f32_16x16x32_fp8_fp8 %0, %1, %2, %0" : "+v"(acc) : "v"(a), "v"(b))

// Raw barrier (no vmcnt drain) with LDS drain + compiler fences.
#define LDS_BARRIER() do { \
  asm volatile("s_waitcnt lgkmcnt(0)" ::: "memory"); \
  __builtin_amdgcn_s_barrier(); \
  asm volatile("" ::: "memory"); \
} while (0)

// C[M,N] bf16 = A[M,K] f32 * B[N,K]^T f32 + bias[N].  M,N mult of 128, K mult of 32.
__global__ __launch_bounds__(256) void gemm_nt_bias(
    const float* __restrict__ A, const float* __restrict__ B,
    const float* __restrict__ bias, unsigned short* __restrict__ C,
    int M, int N, int K)
{
  __shared__ __align__(16) short As[128 * 32];
  __shared__ __align__(16) short Bs[128 * 32];
  const int tid = threadIdx.x;
  const int lane = tid & 63, w = tid >> 6;
  const int brow = blockIdx.x * 128, bcol = blockIdx.y * 128;
  const int wrow = (w & 1) * 64, wcol = (w >> 1) * 64;
  const int c16 = lane & 15, kg = lane >> 4;
  f32x4 acc[4][4];
#pragma unroll
  for (int m = 0; m < 4; m++)
#pragma unroll
    for (int n = 0; n < 4; n++) { f32x4 z = {0.f, 0.f, 0.f, 0.f}; acc[m][n] = z; }

  const int lrow = tid >> 1, lk = (tid & 1) * 16;
  const float* ap = A + (size_t)(brow + lrow) * K + lk;
  const float* bp = B + (size_t)(bcol + lrow) * K + lk;
  short* asw = &As[lrow * 32 + lk];
  short* bsw = &Bs[lrow * 32 + lk];

  for (int kb = 0; kb < K; kb += 32) {
    float4 a0 = *(const float4*)(ap + kb);
    float4 a1 = *(const float4*)(ap + kb + 4);
    float4 a2 = *(const float4*)(ap + kb + 8);
    float4 a3 = *(const float4*)(ap + kb + 12);
    float4 b0 = *(const float4*)(bp + kb);
    float4 b1 = *(const float4*)(bp + kb + 4);
    float4 b2 = *(const float4*)(bp + kb + 8);
    float4 b3 = *(const float4*)(bp + kb + 12);
    __syncthreads();
    *(short8*)asw = pack8(a0, a1);
    *(short8*)(asw + 8) = pack8(a2, a3);
    *(short8*)bsw = pack8(b0, b1);
    *(short8*)(bsw + 8) = pack8(b2, b3);
    __syncthreads();
    short8 af[4], bf[4];
#pragma unroll
    for (int m = 0; m < 4; m++) af[m] = *(const short8*)&As[(wrow + m * 16 + c16) * 32 + kg * 8];
#pragma unroll
    for (int n = 0; n < 4; n++) bf[n] = *(const short8*)&Bs[(wcol + n * 16 + c16) * 32 + kg * 8];
#pragma unroll
    for (int m = 0; m < 4; m++)
#pragma unroll
      for (int n = 0; n < 4; n++)
        acc[m][n] = __builtin_amdgcn_mfma_f32_16x16x32_bf16(af[m], bf[n], acc[m][n], 0, 0, 0);
  }
#pragma unroll
  for (int n = 0; n < 4; n++) {
    const int col = bcol + wcol + n * 16 + c16;
    const float bv = bias[col];
#pragma unroll
    for (int m = 0; m < 4; m++) {
#pragma unroll
      for (int i = 0; i < 4; i++) {
        const int row = brow + wrow + m * 16 + kg * 4 + i;
        C[(size_t)row * N + col] = f2bf(acc[m][n][i] + bv);
      }
    }
  }
}

// Encoder GRU scan, fp8 weights, ONE workgroup of 4 waves (1 wave/SIMD,
// 512-reg budget) per direction. Wave w owns output rows [96w,96w+96) for all
// 3 gates = 18 tiles (e = g*6+u). K-chunks 0..8 in AGPR (18x9 u64 = 324 AGPR);
// chunks 9..11 in LDS (110 KB). Combine is fully in-wave (no gacc staging);
// h exchanged via double-buffered 768 B fp8 LDS buffer; ONE lgkm barrier/step.
// W x256, h x64 (e4m3 range), combine folds 1/16384.
__global__ __launch_bounds__(256) __attribute__((amdgpu_waves_per_eu(1, 1)))
void enc_scan7(
    const float* __restrict__ WhhF, const float* __restrict__ bhhF,
    const float* __restrict__ WhhB, const float* __restrict__ bhhB,
    const unsigned short* __restrict__ Gf, const unsigned short* __restrict__ Gb,
    unsigned short* __restrict__ outputs, int L)
{
  const int dir = blockIdx.x;
  const float* Whh = dir ? WhhB : WhhF;
  const float* bhh = dir ? bhhB : bhhF;
  const unsigned short* G = dir ? Gb : Gf;
  const int tid = threadIdx.x, lane = tid & 63, w = tid >> 6;
  const int c16 = lane & 15, kg = lane >> 4;

  extern __shared__ char smem[];
  unsigned long long* wlds = (unsigned long long*)smem;            // 4w*18e*3c*64 u64 = 110592 B
  unsigned long long* h_qd = (unsigned long long*)(smem + 110592); // 2 x 48 u64 (fp8 h, dbuf)
  unsigned char* h8 = (unsigned char*)h_qd;

  // ---- Prologue: load + quantize this wave's weights ----
  unsigned long long wq[18][9];
#pragma unroll
  for (int g = 0; g < 3; g++)
#pragma unroll
    for (int u = 0; u < 6; u++) {
      const int e = g * 6 + u;
      const int row = g * 384 + 96 * w + 16 * u + c16;
      const float* rp = Whh + (size_t)row * 384 + kg * 8;
#pragma unroll
      for (int t = 0; t < 12; t++) {
        float4 x0 = *(const float4*)(rp + t * 32);
        float4 x1 = *(const float4*)(rp + t * 32 + 4);
        unsigned long long q = pack_fp8x8(x0, x1, 256.f);
        if (t < 9) wq[e][t] = q;
        else wlds[(w * 18 + e) * 192 + (t - 9) * 64 + lane] = q;
      }
    }
  float bb[3][6];
  float h_own[6] = {0.f, 0.f, 0.f, 0.f, 0.f, 0.f};
  unsigned short gi[3][6];
  {
    const int s0 = dir ? (L - 1) : 0;
#pragma unroll
    for (int g = 0; g < 3; g++)
#pragma unroll
      for (int u = 0; u < 6; u++) {
        const int row = g * 384 + 96 * w + 16 * u + c16;
        bb[g][u] = bhh[row];
        gi[g][u] = G[(size_t)s0 * 1152 + row];
      }
  }
  if (tid < 96) h_qd[tid] = 0ull;
  __syncthreads();

  const float INV = 1.f / 16384.f;
  for (int si = 0; si < L; ++si) {
    const int s = dir ? (L - 1 - si) : si;
    const int cur = si & 1, nxt = cur ^ 1;

    // ---- MFMA phase: 18 tiles x 12 K-chunks ----
    f32x4 acc[18];
#pragma unroll
    for (int e = 0; e < 18; e++) { f32x4 z = {0.f, 0.f, 0.f, 0.f}; acc[e] = z; }
#pragma unroll
    for (int t = 0; t < 9; t++) {
      const unsigned long long a = h_qd[cur * 48 + 4 * t + kg];
#pragma unroll
      for (int e = 0; e < 18; e++) MFMA8_WA(acc[e], a, wq[e][t]);
    }
#pragma unroll
    for (int c = 0; c < 3; c++) {
      const unsigned long long a = h_qd[cur * 48 + 4 * (9 + c) + kg];
#pragma unroll
      for (int e = 0; e < 18; e++) {
        const unsigned long long b = wlds[(w * 18 + e) * 192 + c * 64 + lane];
        MFMA8_WV(acc[e], a, b);
      }
    }
    asm volatile("s_nop 7\n\ts_nop 7");

    // ---- in-wave combine (redundant across kg; kg==0 lanes store) ----
#pragma unroll
    for (int u = 0; u < 6; u++) {
      const float rg = sigm(bf2f(gi[0][u]) + bb[0][u] + acc[u][0] * INV);
      const float zg = sigm(bf2f(gi[1][u]) + bb[1][u] + acc[6 + u][0] * INV);
      const float ng = tanh_(bf2f(gi[2][u]) + rg * (acc[12 + u][0] * INV + bb[2][u]));
      h_own[u] = (1.f - zg) * ng + zg * h_own[u];
      if (kg == 0) {
        const int row = 96 * w + 16 * u + c16;
        outputs[(size_t)s * 768 + dir * 384 + row] = f2bf(h_own[u]);
        const int pk = __builtin_amdgcn_cvt_pk_fp8_f32(h_own[u] * 64.f, h_own[u] * 64.f, 0, false);
        h8[nxt * 384 + row] = (unsigned char)(pk & 0xFF);
      }
    }
    // ---- prefetch gi for next step (hidden under next MFMA phase) ----
    if (si + 1 < L) {
      const int sn = dir ? (L - 2 - si) : (si + 1);
#pragma unroll
      for (int g = 0; g < 3; g++)
#pragma unroll
        for (int u = 0; u < 6; u++)
          gi[g][u] = G[(size_t)sn * 1152 + g * 384 + 96 * w + 16 * u + c16];
    }
    LDS_BARRIER();  // h8[nxt] visible; own h_qd[cur] reads drained
  }
}

// Decoder GRU scan: 12 WGs x 8 waves, bf16 weights in AGPR (proven in r4).
__global__ __launch_bounds__(512) __attribute__((amdgpu_waves_per_eu(2, 2)))
void dec_scan4(
    const float* __restrict__ Whh, const float* __restrict__ bhh,
    const unsigned short* __restrict__ Gd, const unsigned short* __restrict__ outputs,
    unsigned short* __restrict__ dechs, unsigned int* __restrict__ hxD,
    int* __restrict__ ctrD, int L, int Ksteps)
{
  const int j = blockIdx.x;  // 0..11
  const int tid = threadIdx.x, lane = tid & 63, w = tid >> 6;
  const int c16 = lane & 15, kg = lane >> 4;

  __shared__ __align__(16) unsigned short h_cur[768];
  __shared__ float gacc[3 * 64 * 2];

  int hf[3], gg[3], qq[3];
  short8 wpc0[12], wpc1[12], wpc2[12];
#pragma unroll
  for (int e = 0; e < 3; e++) {
    const int p = 3 * w + e;
    hf[e] = p & 1;
    gg[e] = (p >> 1) >> 2;
    qq[e] = (p >> 1) & 3;
  }
  {
    const float* rp0 = Whh + (size_t)(gg[0] * 768 + 64 * j + 16 * qq[0] + c16) * 768 + hf[0] * 384 + kg * 8;
    const float* rp1 = Whh + (size_t)(gg[1] * 768 + 64 * j + 16 * qq[1] + c16) * 768 + hf[1] * 384 + kg * 8;
    const float* rp2 = Whh + (size_t)(gg[2] * 768 + 64 * j + 16 * qq[2] + c16) * 768 + hf[2] * 384 + kg * 8;
#pragma unroll
    for (int t = 0; t < 12; t++) {
      wpc0[t] = pack8(*(const float4*)(rp0 + t * 32), *(const float4*)(rp0 + t * 32 + 4));
      wpc1[t] = pack8(*(const float4*)(rp1 + t * 32), *(const float4*)(rp1 + t * 32 + 4));
      wpc2[t] = pack8(*(const float4*)(rp2 + t * 32), *(const float4*)(rp2 + t * 32 + 4));
    }
  }
  const unsigned short* outLast = outputs + (size_t)(L - 1) * 768;
  const int hrow = 64 * j + tid;  // combine row (tid<64)
  float bb0 = 0.f, bb1 = 0.f, bb2 = 0.f, h_own = 0.f;
  if (tid < 64) {
    bb0 = bhh[hrow]; bb1 = bhh[768 + hrow]; bb2 = bhh[1536 + hrow];
    h_own = bf2f(outLast[hrow]);
  }
  if (tid < 384) ((unsigned*)h_cur)[tid] = ((const unsigned*)outLast)[tid];
  __syncthreads();

  for (int s = 0; s < Ksteps; ++s) {
    float gi0 = 0.f, gi1 = 0.f, gi2 = 0.f;
    if (tid < 64) {
      const size_t gb = (size_t)s * 2304 + hrow;
      gi0 = bf2f(Gd[gb]); gi1 = bf2f(Gd[gb + 768]); gi2 = bf2f(Gd[gb + 1536]);
    }
    if (s > 0) {
      if (tid == 0)
        while (__hip_atomic_load(&ctrD[s - 1], __ATOMIC_ACQUIRE, __HIP_MEMORY_SCOPE_AGENT) < 12)
          __builtin_amdgcn_s_sleep(1);
      __syncthreads();
      if (tid < 384) {
        unsigned v = __hip_atomic_load(&hxD[((s - 1) & 1) * 384 + tid],
                                       __ATOMIC_RELAXED, __HIP_MEMORY_SCOPE_AGENT);
        ((unsigned*)h_cur)[tid] = v;
      }
      __syncthreads();
    }
    f32x4 acc0 = {0.f, 0.f, 0.f, 0.f}, acc1 = {0.f, 0.f, 0.f, 0.f}, acc2 = {0.f, 0.f, 0.f, 0.f};
#pragma unroll
    for (int t = 0; t < 12; t++) {
      short8 a0 = *(const short8*)&h_cur[hf[0] * 384 + t * 32 + kg * 8];
      MFMA_AB(acc0, a0, wpc0[t]);
      short8 a1 = *(const short8*)&h_cur[hf[1] * 384 + t * 32 + kg * 8];
      MFMA_AB(acc1, a1, wpc1[t]);
      short8 a2 = *(const short8*)&h_cur[hf[2] * 384 + t * 32 + kg * 8];
      MFMA_AB(acc2, a2, wpc2[t]);
    }
    asm volatile("s_nop 7\n\ts_nop 7");
    if (kg == 0) {
      gacc[(gg[0] * 64 + 16 * qq[0] + c16) * 2 + hf[0]] = acc0[0];
      gacc[(gg[1] * 64 + 16 * qq[1] + c16) * 2 + hf[1]] = acc1[0];
      gacc[(gg[2] * 64 + 16 * qq[2] + c16) * 2 + hf[2]] = acc2[0];
    }
    __syncthreads();
    if (tid < 64) {
      const float s0 = gacc[(0 * 64 + tid) * 2] + gacc[(0 * 64 + tid) * 2 + 1];
      const float s1 = gacc[(1 * 64 + tid) * 2] + gacc[(1 * 64 + tid) * 2 + 1];
      const float s2 = gacc[(2 * 64 + tid) * 2] + gacc[(2 * 64 + tid) * 2 + 1];
      const float rg = sigm(gi0 + bb0 + s0);
      const float zg = sigm(gi1 + bb1 + s1);
      const float ng = tanh_(gi2 + bb2 + rg * s2);
      h_own = (1.f - zg) * ng + zg * h_own;
      const unsigned short hb = f2bf(h_own);
      dechs[(size_t)s * 768 + hrow] = hb;
      const unsigned partner = (unsigned)__shfl_down((int)hb, 1) & 0xFFFFu;
      if ((tid & 1) == 0)
        __hip_atomic_store(&hxD[(s & 1) * 384 + 32 * j + (tid >> 1)],
                           ((unsigned)hb & 0xFFFFu) | (partner << 16),
                           __ATOMIC_RELAXED, __HIP_MEMORY_SCOPE_AGENT);
    }
    __syncthreads();
    if (tid == 0)
      __hip_atomic_fetch_add(&ctrD[s], 1, __ATOMIC_RELEASE, __HIP_MEMORY_SCOPE_AGENT);
  }
}

__global__ void gather_dec(const unsigned short* __restrict__ outputs,
                           const int* __restrict__ breaks,
                           float* __restrict__ din, int L)
{
  const int b = blockIdx.x;
  const int start = b ? breaks[b - 1] : 0;
  const unsigned short* src = outputs + (size_t)start * 768;
  for (int d = threadIdx.x; d < 768; d += blockDim.x)
    din[(size_t)b * 768 + d] = bf2f(src[d]);
}

// C[M,N] f32 = A[M,K] bf16 * B[N,K]^T bf16 (scores = dechs . outputs^T)
__global__ __launch_bounds__(256) void gemm_score(
    const unsigned short* __restrict__ A, const unsigned short* __restrict__ B,
    float* __restrict__ C, int M, int N, int K)
{
  __shared__ __align__(16) short As[128 * 32];
  __shared__ __align__(16) short Bs[128 * 32];
  const int tid = threadIdx.x;
  const int lane = tid & 63, w = tid >> 6;
  const int brow = blockIdx.x * 128, bcol = blockIdx.y * 128;
  const int wrow = (w & 1) * 64, wcol = (w >> 1) * 64;
  const int c16 = lane & 15, kg = lane >> 4;
  f32x4 acc[4][4];
#pragma unroll
  for (int m = 0; m < 4; m++)
#pragma unroll
    for (int n = 0; n < 4; n++) { f32x4 z = {0.f, 0.f, 0.f, 0.f}; acc[m][n] = z; }

  const int lrow = tid >> 1, lk = (tid & 1) * 16;
  const unsigned short* ap = A + (size_t)(brow + lrow) * K + lk;
  const unsigned short* bp = B + (size_t)(bcol + lrow) * K + lk;
  short* asw = &As[lrow * 32 + lk];
  short* bsw = &Bs[lrow * 32 + lk];

  for (int kb = 0; kb < K; kb += 32) {
    short8 a0 = *(const short8*)(ap + kb);
    short8 a1 = *(const short8*)(ap + kb + 8);
    short8 b0 = *(const short8*)(bp + kb);
    short8 b1 = *(const short8*)(bp + kb + 8);
    __syncthreads();
    *(short8*)asw = a0;
    *(short8*)(asw + 8) = a1;
    *(short8*)bsw = b0;
    *(short8*)(bsw + 8) = b1;
    __syncthreads();
    short8 af[4], bf[4];
#pragma unroll
    for (int m = 0; m < 4; m++) af[m] = *(const short8*)&As[(wrow + m * 16 + c16) * 32 + kg * 8];
#pragma unroll
    for (int n = 0; n < 4; n++) bf[n] = *(const short8*)&Bs[(wcol + n * 16 + c16) * 32 + kg * 8];
#pragma unroll
    for (int m = 0; m < 4; m++)
#pragma unroll
      for (int n = 0; n < 4; n++)
        acc[m][n] = __builtin_amdgcn_mfma_f32_16x16x32_bf16(af[m], bf[n], acc[m][n], 0, 0, 0);
  }
#pragma unroll
  for (int n = 0; n < 4; n++) {
    const int col = bcol + wcol + n * 16 + c16;
#pragma unroll
    for (int m = 0; m < 4; m++) {
#pragma unroll
      for (int i = 0; i < 4; i++) {
        const int row = brow + wrow + m * 16 + kg * 4 + i;
        C[(size_t)row * N + col] = acc[m][n][i];
      }
    }
  }
}

// Masked logsumexp over scores[k][start..L) minus score at target.
__global__ __launch_bounds__(256) void loss2(
    const float* __restrict__ scores, const int* __restrict__ breaks,
    float* __restrict__ lossk, int L)
{
  const int k = blockIdx.x;
  const int start = k ? breaks[k - 1] : 0;
  const int target = breaks[k];
  const float* row = scores + (size_t)k * L;
  __shared__ float wm[4], wss[4];
  float m = -3.4e38f, ss = 0.f;
  for (int p = start + threadIdx.x; p < L; p += 256) {
    const float v = row[p];
    if (v > m) { ss = ss * __expf(m - v) + 1.f; m = v; }
    else ss += __expf(v - m);
  }
#pragma unroll
  for (int off = 32; off > 0; off >>= 1) {
    const float mo = __shfl_down(m, off);
    const float so = __shfl_down(ss, off);
    const float mn = fmaxf(m, mo);
    ss = ss * __expf(m - mn) + so * __expf(mo - mn);
    m = mn;
  }
  if ((threadIdx.x & 63) == 0) { wm[threadIdx.x >> 6] = m; wss[threadIdx.x >> 6] = ss; }
  __syncthreads();
  if (threadIdx.x == 0) {
    float M = wm[0], S = wss[0];
#pragma unroll
    for (int q = 1; q < 4; ++q) {
      const float mn = fmaxf(M, wm[q]);
      S = S * __expf(M - mn) + wss[q] * __expf(wm[q] - mn);
      M = mn;
    }
    lossk[k] = (M + __logf(S)) - row[target];
  }
}

__global__ void final_reduce(const float* __restrict__ lossk, float* __restrict__ out, int K)
{
  __shared__ float buf[256];
  float s = 0.f;
  for (int idx = threadIdx.x; idx < K; idx += 256) s += lossk[idx];
  buf[threadIdx.x] = s;
  __syncthreads();
  for (int off = 128; off > 0; off >>= 1) {
    if (threadIdx.x < off) buf[threadIdx.x] += buf[threadIdx.x + off];
    __syncthreads();
  }
  if (threadIdx.x == 0) out[0] = buf[0];
}

extern "C" void kernel_launch(void* const* d_in, const int* in_sizes, int n_in,
                              void* d_out, int out_size, void* d_ws, size_t ws_size,
                              hipStream_t stream)
{
  const float* emb  = (const float*)d_in[0];
  const float* wihF = (const float*)d_in[1];
  const float* whhF = (const float*)d_in[2];
  const float* bihF = (const float*)d_in[3];
  const float* bhhF = (const float*)d_in[4];
  const float* wihB = (const float*)d_in[5];
  const float* whhB = (const float*)d_in[6];
  const float* bihB = (const float*)d_in[7];
  const float* bhhB = (const float*)d_in[8];
  const float* dwih = (const float*)d_in[9];
  const float* dwhh = (const float*)d_in[10];
  const float* dbih = (const float*)d_in[11];
  const float* dbhh = (const float*)d_in[12];
  const int*   brks = (const int*)d_in[13];
  const int L = in_sizes[0] / 768;
  const int K = in_sizes[13];

  auto pad = [](size_t b) { return (b + 255) & ~(size_t)255; };
  const size_t szG   = pad((size_t)L * 1152 * 2);
  const size_t szOut = pad((size_t)L * 768 * 2);
  const size_t szGd  = pad((size_t)K * 2304 * 2);
  const size_t szDin = pad((size_t)K * 768 * 4);
  const size_t szDhs = pad((size_t)K * 768 * 2);
  const size_t szLk  = pad((size_t)K * 4);
  const size_t szHx  = pad(2 * 384 * 4);
  const size_t szCtr = pad((size_t)K * 4);

  char* ws = (char*)d_ws;
  size_t off = 0;
  auto carve = [&](size_t bytes) -> char* { char* p = ws + off; off += bytes; return p; };
  unsigned short* Gf   = (unsigned short*)carve(szG);
  unsigned short* Gb   = (unsigned short*)carve(szG);
  unsigned short* outs = (unsigned short*)carve(szOut);
  unsigned short* Gd   = (unsigned short*)carve(szGd);
  float*          din  = (float*)carve(szDin);
  unsigned short* dhs  = (unsigned short*)carve(szDhs);
  float*          lk   = (float*)carve(szLk);
  unsigned int*   hxD  = (unsigned int*)carve(szHx);
  int*            ctrD = (int*)carve(szCtr);
  float* scores = (float*)Gf;  // alias: Gf dead after enc_scan7; K*L*4 <= szG

  hipMemsetAsync(ctrD, 0, (size_t)K * 4, stream);

  const int encLds = 110592 + 768;
  hipFuncSetAttribute(reinterpret_cast<const void*>(enc_scan7),
                      hipFuncAttributeMaxDynamicSharedMemorySize, 160 * 1024);

  gemm_nt_bias<<<dim3(L / 128, 9), 256, 0, stream>>>(emb, wihF, bihF, Gf, L, 1152, 768);
  gemm_nt_bias<<<dim3(L / 128, 9), 256, 0, stream>>>(emb, wihB, bihB, Gb, L, 1152, 768);
  enc_scan7<<<2, 256, encLds, stream>>>(whhF, bhhF, whhB, bhhB, Gf, Gb, outs, L);
  gather_dec<<<K, 256, 0, stream>>>(outs, brks, din, L);
  gemm_nt_bias<<<dim3(K / 128, 18), 256, 0, stream>>>(din, dwih, dbih, Gd, K, 2304, 768);
  dec_scan4<<<12, 512, 0, stream>>>(dwhh, dbhh, Gd, outs, dhs, hxD, ctrD, L, K);
  gemm_score<<<dim3(K / 128, L / 128), 256, 0, stream>>>(dhs, outs, scores, K, L, 768);
  loss2<<<K, 256, 0, stream>>>(scores, brks, lk, L);
  final_reduce<<<1, 256, 0, stream>>>(lk, (float*)d_out, K);
}

// Round 8
// 51418.323 us; speedup vs baseline: 1.8721x; 1.8721x over previous
//
#include <hip/hip_runtime.h>
#include <hip/hip_bf16.h>
#include <stdint.h>

typedef __attribute__((ext_vector_type(8))) short short8;
typedef __attribute__((ext_vector_type(4))) float f32x4;

__device__ __forceinline__ unsigned short f2bf(float f) {
  union { float f; unsigned u; } v; v.f = f;
  unsigned r = v.u + 0x7FFFu + ((v.u >> 16) & 1u);
  return (unsigned short)(r >> 16);
}
__device__ __forceinline__ float bf2f(unsigned short h) {
  union { unsigned u; float f; } v; v.u = ((unsigned)h) << 16;
  return v.f;
}
__device__ __forceinline__ float sigm(float x) {
  x = fminf(fmaxf(x, -30.f), 30.f);
  return 1.f / (1.f + __expf(-x));
}
__device__ __forceinline__ float tanh_(float x) {
  x = fminf(fmaxf(x, -15.f), 15.f);
  float t = __expf(2.f * x);
  return (t - 1.f) / (t + 1.f);
}
__device__ __forceinline__ short8 pack8(float4 u, float4 v) {
  short8 r;
  r[0] = (short)f2bf(u.x); r[1] = (short)f2bf(u.y); r[2] = (short)f2bf(u.z); r[3] = (short)f2bf(u.w);
  r[4] = (short)f2bf(v.x); r[5] = (short)f2bf(v.y); r[6] = (short)f2bf(v.z); r[7] = (short)f2bf(v.w);
  return r;
}
// Pack 8 f32 (pre-scaled) into 8 e4m3 bytes (one u64).
__device__ __forceinline__ unsigned long long pack_fp8x8(float4 u, float4 v, float scale) {
  int lo = 0, hi = 0;
  lo = __builtin_amdgcn_cvt_pk_fp8_f32(u.x * scale, u.y * scale, lo, false);
  lo = __builtin_amdgcn_cvt_pk_fp8_f32(u.z * scale, u.w * scale, lo, true);
  hi = __builtin_amdgcn_cvt_pk_fp8_f32(v.x * scale, v.y * scale, hi, false);
  hi = __builtin_amdgcn_cvt_pk_fp8_f32(v.z * scale, v.w * scale, hi, true);
  return ((unsigned long long)(unsigned)lo) | (((unsigned long long)(unsigned)hi) << 32);
}

// bf16 MFMA with B pinned to AGPRs.
#define MFMA_AB(acc, a, b) \
  asm("v_mfma_f32_16x16x32_bf16 %0, %1, %2, %0" : "+v"(acc) : "v"(a), "a"(b))
// fp8 MFMA: acc in VGPR; B from AGPR (persistent weights) or VGPR (LDS/VGPR-staged).
#define MFMA8_WA(acc, a, b) \
  asm("v_mfma_f32_16x16x32_fp8_fp8 %0, %1, %2, %0" : "+v"(acc) : "v"(a), "a"(b))
#define MFMA8_WV(acc, a, b) \
  asm("v_mfma_f32_16x16x32_fp8_fp8 %0, %1, %2, %0" : "+v"(acc) : "v"(a), "v"(b))

// Raw barrier (no vmcnt drain) with LDS drain + compiler fences.
#define LDS_BARRIER() do { \
  asm volatile("s_waitcnt lgkmcnt(0)" ::: "memory"); \
  __builtin_amdgcn_s_barrier(); \
  asm volatile("" ::: "memory"); \
} while (0)

// C[M,N] bf16 = A[M,K] f32 * B[N,K]^T f32 + bias[N].  M,N mult of 128, K mult of 32.
__global__ __launch_bounds__(256) void gemm_nt_bias(
    const float* __restrict__ A, const float* __restrict__ B,
    const float* __restrict__ bias, unsigned short* __restrict__ C,
    int M, int N, int K)
{
  __shared__ __align__(16) short As[128 * 32];
  __shared__ __align__(16) short Bs[128 * 32];
  const int tid = threadIdx.x;
  const int lane = tid & 63, w = tid >> 6;
  const int brow = blockIdx.x * 128, bcol = blockIdx.y * 128;
  const int wrow = (w & 1) * 64, wcol = (w >> 1) * 64;
  const int c16 = lane & 15, kg = lane >> 4;
  f32x4 acc[4][4];
#pragma unroll
  for (int m = 0; m < 4; m++)
#pragma unroll
    for (int n = 0; n < 4; n++) { f32x4 z = {0.f, 0.f, 0.f, 0.f}; acc[m][n] = z; }

  const int lrow = tid >> 1, lk = (tid & 1) * 16;
  const float* ap = A + (size_t)(brow + lrow) * K + lk;
  const float* bp = B + (size_t)(bcol + lrow) * K + lk;
  short* asw = &As[lrow * 32 + lk];
  short* bsw = &Bs[lrow * 32 + lk];

  for (int kb = 0; kb < K; kb += 32) {
    float4 a0 = *(const float4*)(ap + kb);
    float4 a1 = *(const float4*)(ap + kb + 4);
    float4 a2 = *(const float4*)(ap + kb + 8);
    float4 a3 = *(const float4*)(ap + kb + 12);
    float4 b0 = *(const float4*)(bp + kb);
    float4 b1 = *(const float4*)(bp + kb + 4);
    float4 b2 = *(const float4*)(bp + kb + 8);
    float4 b3 = *(const float4*)(bp + kb + 12);
    __syncthreads();
    *(short8*)asw = pack8(a0, a1);
    *(short8*)(asw + 8) = pack8(a2, a3);
    *(short8*)bsw = pack8(b0, b1);
    *(short8*)(bsw + 8) = pack8(b2, b3);
    __syncthreads();
    short8 af[4], bf[4];
#pragma unroll
    for (int m = 0; m < 4; m++) af[m] = *(const short8*)&As[(wrow + m * 16 + c16) * 32 + kg * 8];
#pragma unroll
    for (int n = 0; n < 4; n++) bf[n] = *(const short8*)&Bs[(wcol + n * 16 + c16) * 32 + kg * 8];
#pragma unroll
    for (int m = 0; m < 4; m++)
#pragma unroll
      for (int n = 0; n < 4; n++)
        acc[m][n] = __builtin_amdgcn_mfma_f32_16x16x32_bf16(af[m], bf[n], acc[m][n], 0, 0, 0);
  }
#pragma unroll
  for (int n = 0; n < 4; n++) {
    const int col = bcol + wcol + n * 16 + c16;
    const float bv = bias[col];
#pragma unroll
    for (int m = 0; m < 4; m++) {
#pragma unroll
      for (int i = 0; i < 4; i++) {
        const int row = brow + wrow + m * 16 + kg * 4 + i;
        C[(size_t)row * N + col] = f2bf(acc[m][n][i] + bv);
      }
    }
  }
}

// Encoder GRU scan, fp8 weights, ONE workgroup of 4 waves (1 wave/SIMD) per
// direction. Wave w owns rows [96w,96w+96) x 3 gates = 18 tiles (e=g*6+u).
// Register plan (both caps respected):
//   AGPR: tiles 0..14, chunks 0..7  = 120 u64 = 240 AGPR (cap 256)
//   VGPR: tiles 15..17 chunks 0..7 (24 u64) + tiles 0..11 chunks 8..11 (48 u64)
//         = 144 regs; + 24 acc + ~55 temps ~= 223 arch (cap 256)
//   LDS : tiles 12..17, chunks 8..11 = 24 u64/wave (48 KB static)
// 3 passes/step (u-pair each) keep acc at 6 f32x4. In-wave combine, one
// lgkm-only barrier/step, gi prefetched a step ahead. W x256, h x64.
__global__ __launch_bounds__(256) __attribute__((amdgpu_waves_per_eu(1, 1)))
void enc_scan8(
    const float* __restrict__ WhhF, const float* __restrict__ bhhF,
    const float* __restrict__ WhhB, const float* __restrict__ bhhB,
    const unsigned short* __restrict__ Gf, const unsigned short* __restrict__ Gb,
    unsigned short* __restrict__ outputs, int L)
{
  const int dir = blockIdx.x;
  const float* Whh = dir ? WhhB : WhhF;
  const float* bhh = dir ? bhhB : bhhF;
  const unsigned short* G = dir ? Gb : Gf;
  const int tid = threadIdx.x, lane = tid & 63, w = tid >> 6;
  const int c16 = lane & 15, kg = lane >> 4;

  __shared__ unsigned long long wlds[4 * 24 * 64];  // 49152 B
  __shared__ unsigned long long h_qd[96];           // 2 x 384 fp8 bytes
  unsigned char* h8 = (unsigned char*)h_qd;

  // ---- Prologue: load + quantize this wave's weights, route to storage ----
  unsigned long long wqa[15][8];   // AGPR-destined
  unsigned long long wqv1[3][8];   // VGPR: tiles 15..17, chunks 0..7
  unsigned long long wqv2[12][4];  // VGPR: tiles 0..11, chunks 8..11
#pragma unroll
  for (int g = 0; g < 3; g++)
#pragma unroll
    for (int u = 0; u < 6; u++) {
      const int e = g * 6 + u;
      const int row = g * 384 + 96 * w + 16 * u + c16;
      const float* rp = Whh + (size_t)row * 384 + kg * 8;
#pragma unroll
      for (int t = 0; t < 12; t++) {
        float4 x0 = *(const float4*)(rp + t * 32);
        float4 x1 = *(const float4*)(rp + t * 32 + 4);
        unsigned long long q = pack_fp8x8(x0, x1, 256.f);
        if (t < 8) {
          if (e < 15) wqa[e][t] = q;
          else wqv1[e - 15][t] = q;
        } else {
          if (e < 12) wqv2[e][t - 8] = q;
          else wlds[(w * 24 + (e - 12) * 4 + (t - 8)) * 64 + lane] = q;
        }
      }
    }
  float bb[3][6];
  float h_own[6] = {0.f, 0.f, 0.f, 0.f, 0.f, 0.f};
  unsigned short gi[3][6];
  {
    const int s0 = dir ? (L - 1) : 0;
#pragma unroll
    for (int g = 0; g < 3; g++)
#pragma unroll
      for (int u = 0; u < 6; u++) {
        const int row = g * 384 + 96 * w + 16 * u + c16;
        bb[g][u] = bhh[row];
        gi[g][u] = G[(size_t)s0 * 1152 + row];
      }
  }
  if (tid < 96) h_qd[tid] = 0ull;
  __syncthreads();

// route chunk t<8 for tile E (compile-time folded)
#define MF8LO(acc, E, t) do { \
    if ((E) < 15) MFMA8_WA(acc, a, wqa[E][t]); \
    else MFMA8_WV(acc, a, wqv1[(E) - 15][t]); } while (0)

  const float INV = 1.f / 16384.f;
  for (int si = 0; si < L; ++si) {
    const int s = dir ? (L - 1 - si) : si;
    const int cur = si & 1, nxt = cur ^ 1;

#pragma unroll
    for (int p = 0; p < 3; ++p) {
      const int e0 = 2 * p, e1 = 2 * p + 1;           // r-gate tiles
      const int e2 = 6 + 2 * p, e3 = 7 + 2 * p;       // z-gate tiles
      const int e4 = 12 + 2 * p, e5 = 13 + 2 * p;     // n-gate tiles
      f32x4 aR0 = {0.f, 0.f, 0.f, 0.f}, aR1 = {0.f, 0.f, 0.f, 0.f};
      f32x4 aZ0 = {0.f, 0.f, 0.f, 0.f}, aZ1 = {0.f, 0.f, 0.f, 0.f};
      f32x4 aN0 = {0.f, 0.f, 0.f, 0.f}, aN1 = {0.f, 0.f, 0.f, 0.f};
#pragma unroll
      for (int t = 0; t < 8; ++t) {
        const unsigned long long a = h_qd[cur * 48 + 4 * t + kg];
        MF8LO(aR0, e0, t); MF8LO(aR1, e1, t);
        MF8LO(aZ0, e2, t); MF8LO(aZ1, e3, t);
        MF8LO(aN0, e4, t); MF8LO(aN1, e5, t);
      }
#pragma unroll
      for (int t = 8; t < 12; ++t) {
        const unsigned long long a = h_qd[cur * 48 + 4 * t + kg];
        MFMA8_WV(aR0, a, wqv2[e0][t - 8]);
        MFMA8_WV(aR1, a, wqv2[e1][t - 8]);
        MFMA8_WV(aZ0, a, wqv2[e2][t - 8]);
        MFMA8_WV(aZ1, a, wqv2[e3][t - 8]);
        {
          const unsigned long long b = wlds[(w * 24 + (e4 - 12) * 4 + (t - 8)) * 64 + lane];
          MFMA8_WV(aN0, a, b);
        }
        {
          const unsigned long long b = wlds[(w * 24 + (e5 - 12) * 4 + (t - 8)) * 64 + lane];
          MFMA8_WV(aN1, a, b);
        }
      }
      asm volatile("s_nop 7\n\ts_nop 7");
      // in-wave combine for u = 2p, 2p+1 (redundant across kg; kg==0 stores)
#pragma unroll
      for (int q = 0; q < 2; ++q) {
        const int u = 2 * p + q;
        const float ar = q ? aR1[0] : aR0[0];
        const float az = q ? aZ1[0] : aZ0[0];
        const float an = q ? aN1[0] : aN0[0];
        const float rg = sigm(bf2f(gi[0][u]) + bb[0][u] + ar * INV);
        const float zg = sigm(bf2f(gi[1][u]) + bb[1][u] + az * INV);
        const float ng = tanh_(bf2f(gi[2][u]) + rg * (an * INV + bb[2][u]));
        h_own[u] = (1.f - zg) * ng + zg * h_own[u];
        if (kg == 0) {
          const int row = 96 * w + 16 * u + c16;
          outputs[(size_t)s * 768 + dir * 384 + row] = f2bf(h_own[u]);
          const int pk = __builtin_amdgcn_cvt_pk_fp8_f32(h_own[u] * 64.f, h_own[u] * 64.f, 0, false);
          h8[nxt * 384 + row] = (unsigned char)(pk & 0xFF);
        }
      }
    }
    // ---- prefetch gi for next step (hidden under next MFMA phase) ----
    if (si + 1 < L) {
      const int sn = dir ? (L - 2 - si) : (si + 1);
#pragma unroll
      for (int g = 0; g < 3; g++)
#pragma unroll
        for (int u = 0; u < 6; u++)
          gi[g][u] = G[(size_t)sn * 1152 + g * 384 + 96 * w + 16 * u + c16];
    }
    LDS_BARRIER();  // h8[nxt] visible; own h_qd[cur] reads drained
  }
#undef MF8LO
}

// Decoder GRU scan: 12 WGs x 8 waves, bf16 weights in AGPR (proven in r4).
__global__ __launch_bounds__(512) __attribute__((amdgpu_waves_per_eu(2, 2)))
void dec_scan4(
    const float* __restrict__ Whh, const float* __restrict__ bhh,
    const unsigned short* __restrict__ Gd, const unsigned short* __restrict__ outputs,
    unsigned short* __restrict__ dechs, unsigned int* __restrict__ hxD,
    int* __restrict__ ctrD, int L, int Ksteps)
{
  const int j = blockIdx.x;  // 0..11
  const int tid = threadIdx.x, lane = tid & 63, w = tid >> 6;
  const int c16 = lane & 15, kg = lane >> 4;

  __shared__ __align__(16) unsigned short h_cur[768];
  __shared__ float gacc[3 * 64 * 2];

  int hf[3], gg[3], qq[3];
  short8 wpc0[12], wpc1[12], wpc2[12];
#pragma unroll
  for (int e = 0; e < 3; e++) {
    const int p = 3 * w + e;
    hf[e] = p & 1;
    gg[e] = (p >> 1) >> 2;
    qq[e] = (p >> 1) & 3;
  }
  {
    const float* rp0 = Whh + (size_t)(gg[0] * 768 + 64 * j + 16 * qq[0] + c16) * 768 + hf[0] * 384 + kg * 8;
    const float* rp1 = Whh + (size_t)(gg[1] * 768 + 64 * j + 16 * qq[1] + c16) * 768 + hf[1] * 384 + kg * 8;
    const float* rp2 = Whh + (size_t)(gg[2] * 768 + 64 * j + 16 * qq[2] + c16) * 768 + hf[2] * 384 + kg * 8;
#pragma unroll
    for (int t = 0; t < 12; t++) {
      wpc0[t] = pack8(*(const float4*)(rp0 + t * 32), *(const float4*)(rp0 + t * 32 + 4));
      wpc1[t] = pack8(*(const float4*)(rp1 + t * 32), *(const float4*)(rp1 + t * 32 + 4));
      wpc2[t] = pack8(*(const float4*)(rp2 + t * 32), *(const float4*)(rp2 + t * 32 + 4));
    }
  }
  const unsigned short* outLast = outputs + (size_t)(L - 1) * 768;
  const int hrow = 64 * j + tid;  // combine row (tid<64)
  float bb0 = 0.f, bb1 = 0.f, bb2 = 0.f, h_own = 0.f;
  if (tid < 64) {
    bb0 = bhh[hrow]; bb1 = bhh[768 + hrow]; bb2 = bhh[1536 + hrow];
    h_own = bf2f(outLast[hrow]);
  }
  if (tid < 384) ((unsigned*)h_cur)[tid] = ((const unsigned*)outLast)[tid];
  __syncthreads();

  for (int s = 0; s < Ksteps; ++s) {
    float gi0 = 0.f, gi1 = 0.f, gi2 = 0.f;
    if (tid < 64) {
      const size_t gb = (size_t)s * 2304 + hrow;
      gi0 = bf2f(Gd[gb]); gi1 = bf2f(Gd[gb + 768]); gi2 = bf2f(Gd[gb + 1536]);
    }
    if (s > 0) {
      if (tid == 0)
        while (__hip_atomic_load(&ctrD[s - 1], __ATOMIC_ACQUIRE, __HIP_MEMORY_SCOPE_AGENT) < 12)
          __builtin_amdgcn_s_sleep(1);
      __syncthreads();
      if (tid < 384) {
        unsigned v = __hip_atomic_load(&hxD[((s - 1) & 1) * 384 + tid],
                                       __ATOMIC_RELAXED, __HIP_MEMORY_SCOPE_AGENT);
        ((unsigned*)h_cur)[tid] = v;
      }
      __syncthreads();
    }
    f32x4 acc0 = {0.f, 0.f, 0.f, 0.f}, acc1 = {0.f, 0.f, 0.f, 0.f}, acc2 = {0.f, 0.f, 0.f, 0.f};
#pragma unroll
    for (int t = 0; t < 12; t++) {
      short8 a0 = *(const short8*)&h_cur[hf[0] * 384 + t * 32 + kg * 8];
      MFMA_AB(acc0, a0, wpc0[t]);
      short8 a1 = *(const short8*)&h_cur[hf[1] * 384 + t * 32 + kg * 8];
      MFMA_AB(acc1, a1, wpc1[t]);
      short8 a2 = *(const short8*)&h_cur[hf[2] * 384 + t * 32 + kg * 8];
      MFMA_AB(acc2, a2, wpc2[t]);
    }
    asm volatile("s_nop 7\n\ts_nop 7");
    if (kg == 0) {
      gacc[(gg[0] * 64 + 16 * qq[0] + c16) * 2 + hf[0]] = acc0[0];
      gacc[(gg[1] * 64 + 16 * qq[1] + c16) * 2 + hf[1]] = acc1[0];
      gacc[(gg[2] * 64 + 16 * qq[2] + c16) * 2 + hf[2]] = acc2[0];
    }
    __syncthreads();
    if (tid < 64) {
      const float s0 = gacc[(0 * 64 + tid) * 2] + gacc[(0 * 64 + tid) * 2 + 1];
      const float s1 = gacc[(1 * 64 + tid) * 2] + gacc[(1 * 64 + tid) * 2 + 1];
      const float s2 = gacc[(2 * 64 + tid) * 2] + gacc[(2 * 64 + tid) * 2 + 1];
      const float rg = sigm(gi0 + bb0 + s0);
      const float zg = sigm(gi1 + bb1 + s1);
      const float ng = tanh_(gi2 + bb2 + rg * s2);
      h_own = (1.f - zg) * ng + zg * h_own;
      const unsigned short hb = f2bf(h_own);
      dechs[(size_t)s * 768 + hrow] = hb;
      const unsigned partner = (unsigned)__shfl_down((int)hb, 1) & 0xFFFFu;
      if ((tid & 1) == 0)
        __hip_atomic_store(&hxD[(s & 1) * 384 + 32 * j + (tid >> 1)],
                           ((unsigned)hb & 0xFFFFu) | (partner << 16),
                           __ATOMIC_RELAXED, __HIP_MEMORY_SCOPE_AGENT);
    }
    __syncthreads();
    if (tid == 0)
      __hip_atomic_fetch_add(&ctrD[s], 1, __ATOMIC_RELEASE, __HIP_MEMORY_SCOPE_AGENT);
  }
}

__global__ void gather_dec(const unsigned short* __restrict__ outputs,
                           const int* __restrict__ breaks,
                           float* __restrict__ din, int L)
{
  const int b = blockIdx.x;
  const int start = b ? breaks[b - 1] : 0;
  const unsigned short* src = outputs + (size_t)start * 768;
  for (int d = threadIdx.x; d < 768; d += blockDim.x)
    din[(size_t)b * 768 + d] = bf2f(src[d]);
}

// C[M,N] f32 = A[M,K] bf16 * B[N,K]^T bf16 (scores = dechs . outputs^T)
__global__ __launch_bounds__(256) void gemm_score(
    const unsigned short* __restrict__ A, const unsigned short* __restrict__ B,
    float* __restrict__ C, int M, int N, int K)
{
  __shared__ __align__(16) short As[128 * 32];
  __shared__ __align__(16) short Bs[128 * 32];
  const int tid = threadIdx.x;
  const int lane = tid & 63, w = tid >> 6;
  const int brow = blockIdx.x * 128, bcol = blockIdx.y * 128;
  const int wrow = (w & 1) * 64, wcol = (w >> 1) * 64;
  const int c16 = lane & 15, kg = lane >> 4;
  f32x4 acc[4][4];
#pragma unroll
  for (int m = 0; m < 4; m++)
#pragma unroll
    for (int n = 0; n < 4; n++) { f32x4 z = {0.f, 0.f, 0.f, 0.f}; acc[m][n] = z; }

  const int lrow = tid >> 1, lk = (tid & 1) * 16;
  const unsigned short* ap = A + (size_t)(brow + lrow) * K + lk;
  const unsigned short* bp = B + (size_t)(bcol + lrow) * K + lk;
  short* asw = &As[lrow * 32 + lk];
  short* bsw = &Bs[lrow * 32 + lk];

  for (int kb = 0; kb < K; kb += 32) {
    short8 a0 = *(const short8*)(ap + kb);
    short8 a1 = *(const short8*)(ap + kb + 8);
    short8 b0 = *(const short8*)(bp + kb);
    short8 b1 = *(const short8*)(bp + kb + 8);
    __syncthreads();
    *(short8*)asw = a0;
    *(short8*)(asw + 8) = a1;
    *(short8*)bsw = b0;
    *(short8*)(bsw + 8) = b1;
    __syncthreads();
    short8 af[4], bf[4];
#pragma unroll
    for (int m = 0; m < 4; m++) af[m] = *(const short8*)&As[(wrow + m * 16 + c16) * 32 + kg * 8];
#pragma unroll
    for (int n = 0; n < 4; n++) bf[n] = *(const short8*)&Bs[(wcol + n * 16 + c16) * 32 + kg * 8];
#pragma unroll
    for (int m = 0; m < 4; m++)
#pragma unroll
      for (int n = 0; n < 4; n++)
        acc[m][n] = __builtin_amdgcn_mfma_f32_16x16x32_bf16(af[m], bf[n], acc[m][n], 0, 0, 0);
  }
#pragma unroll
  for (int n = 0; n < 4; n++) {
    const int col = bcol + wcol + n * 16 + c16;
#pragma unroll
    for (int m = 0; m < 4; m++) {
#pragma unroll
      for (int i = 0; i < 4; i++) {
        const int row = brow + wrow + m * 16 + kg * 4 + i;
        C[(size_t)row * N + col] = acc[m][n][i];
      }
    }
  }
}

// Masked logsumexp over scores[k][start..L) minus score at target.
__global__ __launch_bounds__(256) void loss2(
    const float* __restrict__ scores, const int* __restrict__ breaks,
    float* __restrict__ lossk, int L)
{
  const int k = blockIdx.x;
  const int start = k ? breaks[k - 1] : 0;
  const int target = breaks[k];
  const float* row = scores + (size_t)k * L;
  __shared__ float wm[4], wss[4];
  float m = -3.4e38f, ss = 0.f;
  for (int p = start + threadIdx.x; p < L; p += 256) {
    const float v = row[p];
    if (v > m) { ss = ss * __expf(m - v) + 1.f; m = v; }
    else ss += __expf(v - m);
  }
#pragma unroll
  for (int off = 32; off > 0; off >>= 1) {
    const float mo = __shfl_down(m, off);
    const float so = __shfl_down(ss, off);
    const float mn = fmaxf(m, mo);
    ss = ss * __expf(m - mn) + so * __expf(mo - mn);
    m = mn;
  }
  if ((threadIdx.x & 63) == 0) { wm[threadIdx.x >> 6] = m; wss[threadIdx.x >> 6] = ss; }
  __syncthreads();
  if (threadIdx.x == 0) {
    float M = wm[0], S = wss[0];
#pragma unroll
    for (int q = 1; q < 4; ++q) {
      const float mn = fmaxf(M, wm[q]);
      S = S * __expf(M - mn) + wss[q] * __expf(wm[q] - mn);
      M = mn;
    }
    lossk[k] = (M + __logf(S)) - row[target];
  }
}

__global__ void final_reduce(const float* __restrict__ lossk, float* __restrict__ out, int K)
{
  __shared__ float buf[256];
  float s = 0.f;
  for (int idx = threadIdx.x; idx < K; idx += 256) s += lossk[idx];
  buf[threadIdx.x] = s;
  __syncthreads();
  for (int off = 128; off > 0; off >>= 1) {
    if (threadIdx.x < off) buf[threadIdx.x] += buf[threadIdx.x + off];
    __syncthreads();
  }
  if (threadIdx.x == 0) out[0] = buf[0];
}

extern "C" void kernel_launch(void* const* d_in, const int* in_sizes, int n_in,
                              void* d_out, int out_size, void* d_ws, size_t ws_size,
                              hipStream_t stream)
{
  const float* emb  = (const float*)d_in[0];
  const float* wihF = (const float*)d_in[1];
  const float* whhF = (const float*)d_in[2];
  const float* bihF = (const float*)d_in[3];
  const float* bhhF = (const float*)d_in[4];
  const float* wihB = (const float*)d_in[5];
  const float* whhB = (const float*)d_in[6];
  const float* bihB = (const float*)d_in[7];
  const float* bhhB = (const float*)d_in[8];
  const float* dwih = (const float*)d_in[9];
  const float* dwhh = (const float*)d_in[10];
  const float* dbih = (const float*)d_in[11];
  const float* dbhh = (const float*)d_in[12];
  const int*   brks = (const int*)d_in[13];
  const int L = in_sizes[0] / 768;
  const int K = in_sizes[13];

  auto pad = [](size_t b) { return (b + 255) & ~(size_t)255; };
  const size_t szG   = pad((size_t)L * 1152 * 2);
  const size_t szOut = pad((size_t)L * 768 * 2);
  const size_t szGd  = pad((size_t)K * 2304 * 2);
  const size_t szDin = pad((size_t)K * 768 * 4);
  const size_t szDhs = pad((size_t)K * 768 * 2);
  const size_t szLk  = pad((size_t)K * 4);
  const size_t szHx  = pad(2 * 384 * 4);
  const size_t szCtr = pad((size_t)K * 4);

  char* ws = (char*)d_ws;
  size_t off = 0;
  auto carve = [&](size_t bytes) -> char* { char* p = ws + off; off += bytes; return p; };
  unsigned short* Gf   = (unsigned short*)carve(szG);
  unsigned short* Gb   = (unsigned short*)carve(szG);
  unsigned short* outs = (unsigned short*)carve(szOut);
  unsigned short* Gd   = (unsigned short*)carve(szGd);
  float*          din  = (float*)carve(szDin);
  unsigned short* dhs  = (unsigned short*)carve(szDhs);
  float*          lk   = (float*)carve(szLk);
  unsigned int*   hxD  = (unsigned int*)carve(szHx);
  int*            ctrD = (int*)carve(szCtr);
  float* scores = (float*)Gf;  // alias: Gf dead after enc_scan8; K*L*4 <= szG

  hipMemsetAsync(ctrD, 0, (size_t)K * 4, stream);

  gemm_nt_bias<<<dim3(L / 128, 9), 256, 0, stream>>>(emb, wihF, bihF, Gf, L, 1152, 768);
  gemm_nt_bias<<<dim3(L / 128, 9), 256, 0, stream>>>(emb, wihB, bihB, Gb, L, 1152, 768);
  enc_scan8<<<2, 256, 0, stream>>>(whhF, bhhF, whhB, bhhB, Gf, Gb, outs, L);
  gather_dec<<<K, 256, 0, stream>>>(outs, brks, din, L);
  gemm_nt_bias<<<dim3(K / 128, 18), 256, 0, stream>>>(din, dwih, dbih, Gd, K, 2304, 768);
  dec_scan4<<<12, 512, 0, stream>>>(dwhh, dbhh, Gd, outs, dhs, hxD, ctrD, L, K);
  gemm_score<<<dim3(K / 128, L / 128), 256, 0, stream>>>(dhs, outs, scores, K, L, 768);
  loss2<<<K, 256, 0, stream>>>(scores, brks, lk, L);
  final_reduce<<<1, 256, 0, stream>>>(lk, (float*)d_out, K);
}

// Round 11
// 36635.358 us; speedup vs baseline: 2.6275x; 1.4035x over previous
//
#include <hip/hip_runtime.h>
#include <hip/hip_bf16.h>
#include <stdint.h>

typedef __attribute__((ext_vector_type(8))) short short8;
typedef __attribute__((ext_vector_type(4))) float f32x4;
typedef unsigned long long u64;

__device__ __forceinline__ unsigned short f2bf(float f) {
  union { float f; unsigned u; } v; v.f = f;
  unsigned r = v.u + 0x7FFFu + ((v.u >> 16) & 1u);
  return (unsigned short)(r >> 16);
}
__device__ __forceinline__ float bf2f(unsigned short h) {
  union { unsigned u; float f; } v; v.u = ((unsigned)h) << 16;
  return v.f;
}
__device__ __forceinline__ float sigm(float x) {
  x = fminf(fmaxf(x, -30.f), 30.f);
  return 1.f / (1.f + __expf(-x));
}
__device__ __forceinline__ float tanh_(float x) {
  x = fminf(fmaxf(x, -15.f), 15.f);
  float t = __expf(2.f * x);
  return (t - 1.f) / (t + 1.f);
}
__device__ __forceinline__ short8 pack8(float4 u, float4 v) {
  short8 r;
  r[0] = (short)f2bf(u.x); r[1] = (short)f2bf(u.y); r[2] = (short)f2bf(u.z); r[3] = (short)f2bf(u.w);
  r[4] = (short)f2bf(v.x); r[5] = (short)f2bf(v.y); r[6] = (short)f2bf(v.z); r[7] = (short)f2bf(v.w);
  return r;
}
// Pack 8 f32 (pre-scaled) into 8 e4m3 bytes (one u64).
__device__ __forceinline__ u64 pack_fp8x8(float4 u, float4 v, float scale) {
  int lo = 0, hi = 0;
  lo = __builtin_amdgcn_cvt_pk_fp8_f32(u.x * scale, u.y * scale, lo, false);
  lo = __builtin_amdgcn_cvt_pk_fp8_f32(u.z * scale, u.w * scale, lo, true);
  hi = __builtin_amdgcn_cvt_pk_fp8_f32(v.x * scale, v.y * scale, hi, false);
  hi = __builtin_amdgcn_cvt_pk_fp8_f32(v.z * scale, v.w * scale, hi, true);
  return ((u64)(unsigned)lo) | (((u64)(unsigned)hi) << 32);
}

// bf16 MFMA with B pinned to AGPRs.
#define MFMA_AB(acc, a, b) \
  asm("v_mfma_f32_16x16x32_bf16 %0, %1, %2, %0" : "+v"(acc) : "v"(a), "a"(b))
// fp8 MFMA: acc in VGPR; B from AGPR (persistent weights).
#define MFMA8_WA(acc, a, b) \
  asm("v_mfma_f32_16x16x32_fp8_fp8 %0, %1, %2, %0" : "+v"(acc) : "v"(a), "a"(b))

// Raw barrier (no vmcnt drain) with LDS drain + compiler fences.
#define LDS_BARRIER() do { \
  asm volatile("s_waitcnt lgkmcnt(0)" ::: "memory"); \
  __builtin_amdgcn_s_barrier(); \
  asm volatile("" ::: "memory"); \
} while (0)

// C[M,N] bf16 = A[M,K] f32 * B[N,K]^T f32 + bias[N].  M,N mult of 128, K mult of 32.
__global__ __launch_bounds__(256) void gemm_nt_bias(
    const float* __restrict__ A, const float* __restrict__ B,
    const float* __restrict__ bias, unsigned short* __restrict__ C,
    int M, int N, int K)
{
  __shared__ __align__(16) short As[128 * 32];
  __shared__ __align__(16) short Bs[128 * 32];
  const int tid = threadIdx.x;
  const int lane = tid & 63, w = tid >> 6;
  const int brow = blockIdx.x * 128, bcol = blockIdx.y * 128;
  const int wrow = (w & 1) * 64, wcol = (w >> 1) * 64;
  const int c16 = lane & 15, kg = lane >> 4;
  f32x4 acc[4][4];
#pragma unroll
  for (int m = 0; m < 4; m++)
#pragma unroll
    for (int n = 0; n < 4; n++) { f32x4 z = {0.f, 0.f, 0.f, 0.f}; acc[m][n] = z; }

  const int lrow = tid >> 1, lk = (tid & 1) * 16;
  const float* ap = A + (size_t)(brow + lrow) * K + lk;
  const float* bp = B + (size_t)(bcol + lrow) * K + lk;
  short* asw = &As[lrow * 32 + lk];
  short* bsw = &Bs[lrow * 32 + lk];

  for (int kb = 0; kb < K; kb += 32) {
    float4 a0 = *(const float4*)(ap + kb);
    float4 a1 = *(const float4*)(ap + kb + 4);
    float4 a2 = *(const float4*)(ap + kb + 8);
    float4 a3 = *(const float4*)(ap + kb + 12);
    float4 b0 = *(const float4*)(bp + kb);
    float4 b1 = *(const float4*)(bp + kb + 4);
    float4 b2 = *(const float4*)(bp + kb + 8);
    float4 b3 = *(const float4*)(bp + kb + 12);
    __syncthreads();
    *(short8*)asw = pack8(a0, a1);
    *(short8*)(asw + 8) = pack8(a2, a3);
    *(short8*)bsw = pack8(b0, b1);
    *(short8*)(bsw + 8) = pack8(b2, b3);
    __syncthreads();
    short8 af[4], bf[4];
#pragma unroll
    for (int m = 0; m < 4; m++) af[m] = *(const short8*)&As[(wrow + m * 16 + c16) * 32 + kg * 8];
#pragma unroll
    for (int n = 0; n < 4; n++) bf[n] = *(const short8*)&Bs[(wcol + n * 16 + c16) * 32 + kg * 8];
#pragma unroll
    for (int m = 0; m < 4; m++)
#pragma unroll
      for (int n = 0; n < 4; n++)
        acc[m][n] = __builtin_amdgcn_mfma_f32_16x16x32_bf16(af[m], bf[n], acc[m][n], 0, 0, 0);
  }
#pragma unroll
  for (int n = 0; n < 4; n++) {
    const int col = bcol + wcol + n * 16 + c16;
    const float bv = bias[col];
#pragma unroll
    for (int m = 0; m < 4; m++) {
#pragma unroll
      for (int i = 0; i < 4; i++) {
        const int row = brow + wrow + m * 16 + kg * 4 + i;
        C[(size_t)row * N + col] = f2bf(acc[m][n][i] + bv);
      }
    }
  }
}

// Encoder GRU scan, fp8 weights, 3 WGs x 8 waves per direction.
// WG r owns rows [128r,128r+128); wave w holds wq[3][12] = 72 AGPR for rows
// 128r+16w+c16 (gates r,z,n). In-wave combine (acc[.][0] is kg-redundant,
// layout-verified + empirically proven in rounds 6-8). Cross-WG h exchange
// uses dec_scan4's PROVEN flag protocol: relaxed agent data atomics ->
// vmcnt-draining __syncthreads -> tid0 release fetch_add on per-step counter
// -> tid0 acquire poll -> __syncthreads -> relaxed atomic loads. Hang-proof:
// every WG increments before polling (no circular wait). h is fp8 (96 u32).
__global__ __launch_bounds__(512) __attribute__((amdgpu_waves_per_eu(2, 2)))
void enc_scan11(
    const float* __restrict__ WhhF, const float* __restrict__ bhhF,
    const float* __restrict__ WhhB, const float* __restrict__ bhhB,
    const unsigned short* __restrict__ Gf, const unsigned short* __restrict__ Gb,
    unsigned short* __restrict__ outputs, unsigned int* __restrict__ hxE,
    int* __restrict__ ctrE, int L)
{
  const int dir = blockIdx.x & 1;
  const int r = blockIdx.x >> 1;  // 0..2
  const float* Whh = dir ? WhhB : WhhF;
  const float* bhh = dir ? bhhB : bhhF;
  const unsigned short* G = dir ? Gb : Gf;
  unsigned int* hx = hxE + dir * 2 * 96;  // [ring2][96] u32 (fp8 h, 4 rows/word)
  int* ctr = ctrE + (size_t)dir * L;

  const int tid = threadIdx.x, lane = tid & 63, w = tid >> 6;
  const int c16 = lane & 15, kg = lane >> 4;

  __shared__ __align__(8) u64 h_qd[96];  // [ring2][48] u64 = 2 x 384 fp8 bytes
  unsigned char* h8 = (unsigned char*)h_qd;

  // ---- Prologue: quantize this wave's weights into 72 AGPRs ----
  const int myrow = 128 * r + 16 * w + c16;
  u64 wq[3][12];
  float bb[3];
#pragma unroll
  for (int g = 0; g < 3; g++) {
    const int jrow = g * 384 + myrow;
    bb[g] = bhh[jrow];
    const float* rp = Whh + (size_t)jrow * 384 + kg * 8;
#pragma unroll
    for (int t = 0; t < 12; t++) {
      float4 x0 = *(const float4*)(rp + t * 32);
      float4 x1 = *(const float4*)(rp + t * 32 + 4);
      wq[g][t] = pack_fp8x8(x0, x1, 256.f);
    }
  }
  float h_own = 0.f;  // kg-redundant state for row myrow
  unsigned short gr0, gr1, gr2;
  {
    const int s0 = dir ? (L - 1) : 0;
    const size_t gb = (size_t)s0 * 1152 + myrow;
    gr0 = G[gb]; gr1 = G[gb + 384]; gr2 = G[gb + 768];
  }
  if (tid < 48) h_qd[tid] = 0ull;  // h8[ring 0] = 0
  __syncthreads();

  const float INV = 1.f / 16384.f;
  for (int si = 0; si < L; ++si) {
    const int s = dir ? (L - 1 - si) : si;
    const int cur = si & 1, nxt = cur ^ 1;

    // ---- MFMA: 3 gate-tiles x 12 K-chunks (B in AGPR) ----
    f32x4 a0 = {0.f, 0.f, 0.f, 0.f}, a1 = {0.f, 0.f, 0.f, 0.f}, a2 = {0.f, 0.f, 0.f, 0.f};
#pragma unroll
    for (int t = 0; t < 12; t++) {
      const u64 a = h_qd[cur * 48 + 4 * t + kg];
      MFMA8_WA(a0, a, wq[0][t]);
      MFMA8_WA(a1, a, wq[1][t]);
      MFMA8_WA(a2, a, wq[2][t]);
    }
    asm volatile("s_nop 7\n\ts_nop 7");

    // ---- combine (kg-redundant) ----
    const float rg = sigm(bf2f(gr0) + bb[0] + a0[0] * INV);
    const float zg = sigm(bf2f(gr1) + bb[1] + a1[0] * INV);
    const float ng = tanh_(bf2f(gr2) + rg * (a2[0] * INV + bb[2]));
    h_own = (1.f - zg) * ng + zg * h_own;
    if (kg == 0) {
      outputs[(size_t)s * 768 + dir * 384 + myrow] = f2bf(h_own);
      const int pk = __builtin_amdgcn_cvt_pk_fp8_f32(h_own * 64.f, h_own * 64.f, 0, false);
      h8[nxt * 384 + myrow] = (unsigned char)(pk & 0xFF);
    }
    // prefetch next-step gi (issues now; drained by the publish syncthreads)
    if (si + 1 < L) {
      const int sn = dir ? (L - 2 - si) : (si + 1);
      const size_t gb = (size_t)sn * 1152 + myrow;
      gr0 = G[gb]; gr1 = G[gb + 384]; gr2 = G[gb + 768];
    }

    if (si + 1 < L) {
      LDS_BARRIER();  // h8[nxt] own-strip bytes visible to publishers
      if (tid < 32) {
        const unsigned d = *(const unsigned*)&h8[nxt * 384 + 128 * r + 4 * tid];
        __hip_atomic_store(&hx[nxt * 96 + 32 * r + tid], d,
                           __ATOMIC_RELAXED, __HIP_MEMORY_SCOPE_AGENT);
      }
      __syncthreads();  // vmcnt(0): hx stores complete at coherence point
      if (tid == 0) {
        __hip_atomic_fetch_add(&ctr[si], 1, __ATOMIC_RELEASE, __HIP_MEMORY_SCOPE_AGENT);
        while (__hip_atomic_load(&ctr[si], __ATOMIC_ACQUIRE, __HIP_MEMORY_SCOPE_AGENT) < 3)
          __builtin_amdgcn_s_sleep(1);
      }
      __syncthreads();  // broadcast poll success
      if (tid < 96) {
        const unsigned v = __hip_atomic_load(&hx[nxt * 96 + tid],
                                             __ATOMIC_RELAXED, __HIP_MEMORY_SCOPE_AGENT);
        *(unsigned*)&h8[nxt * 384 + 4 * tid] = v;
      }
      LDS_BARRIER();  // h8[nxt] complete for next step
    }
  }
}

// Decoder GRU scan: 12 WGs x 8 waves, bf16 weights in AGPR (proven in r4-r8).
__global__ __launch_bounds__(512) __attribute__((amdgpu_waves_per_eu(2, 2)))
void dec_scan4(
    const float* __restrict__ Whh, const float* __restrict__ bhh,
    const unsigned short* __restrict__ Gd, const unsigned short* __restrict__ outputs,
    unsigned short* __restrict__ dechs, unsigned int* __restrict__ hxD,
    int* __restrict__ ctrD, int L, int Ksteps)
{
  const int j = blockIdx.x;  // 0..11
  const int tid = threadIdx.x, lane = tid & 63, w = tid >> 6;
  const int c16 = lane & 15, kg = lane >> 4;

  __shared__ __align__(16) unsigned short h_cur[768];
  __shared__ float gacc[3 * 64 * 2];

  int hf[3], gg[3], qq[3];
  short8 wpc0[12], wpc1[12], wpc2[12];
#pragma unroll
  for (int e = 0; e < 3; e++) {
    const int p = 3 * w + e;
    hf[e] = p & 1;
    gg[e] = (p >> 1) >> 2;
    qq[e] = (p >> 1) & 3;
  }
  {
    const float* rp0 = Whh + (size_t)(gg[0] * 768 + 64 * j + 16 * qq[0] + c16) * 768 + hf[0] * 384 + kg * 8;
    const float* rp1 = Whh + (size_t)(gg[1] * 768 + 64 * j + 16 * qq[1] + c16) * 768 + hf[1] * 384 + kg * 8;
    const float* rp2 = Whh + (size_t)(gg[2] * 768 + 64 * j + 16 * qq[2] + c16) * 768 + hf[2] * 384 + kg * 8;
#pragma unroll
    for (int t = 0; t < 12; t++) {
      wpc0[t] = pack8(*(const float4*)(rp0 + t * 32), *(const float4*)(rp0 + t * 32 + 4));
      wpc1[t] = pack8(*(const float4*)(rp1 + t * 32), *(const float4*)(rp1 + t * 32 + 4));
      wpc2[t] = pack8(*(const float4*)(rp2 + t * 32), *(const float4*)(rp2 + t * 32 + 4));
    }
  }
  const unsigned short* outLast = outputs + (size_t)(L - 1) * 768;
  const int hrow = 64 * j + tid;  // combine row (tid<64)
  float bb0 = 0.f, bb1 = 0.f, bb2 = 0.f, h_own = 0.f;
  if (tid < 64) {
    bb0 = bhh[hrow]; bb1 = bhh[768 + hrow]; bb2 = bhh[1536 + hrow];
    h_own = bf2f(outLast[hrow]);
  }
  if (tid < 384) ((unsigned*)h_cur)[tid] = ((const unsigned*)outLast)[tid];
  __syncthreads();

  for (int s = 0; s < Ksteps; ++s) {
    float gi0 = 0.f, gi1 = 0.f, gi2 = 0.f;
    if (tid < 64) {
      const size_t gb = (size_t)s * 2304 + hrow;
      gi0 = bf2f(Gd[gb]); gi1 = bf2f(Gd[gb + 768]); gi2 = bf2f(Gd[gb + 1536]);
    }
    if (s > 0) {
      if (tid == 0)
        while (__hip_atomic_load(&ctrD[s - 1], __ATOMIC_ACQUIRE, __HIP_MEMORY_SCOPE_AGENT) < 12)
          __builtin_amdgcn_s_sleep(1);
      __syncthreads();
      if (tid < 384) {
        unsigned v = __hip_atomic_load(&hxD[((s - 1) & 1) * 384 + tid],
                                       __ATOMIC_RELAXED, __HIP_MEMORY_SCOPE_AGENT);
        ((unsigned*)h_cur)[tid] = v;
      }
      __syncthreads();
    }
    f32x4 acc0 = {0.f, 0.f, 0.f, 0.f}, acc1 = {0.f, 0.f, 0.f, 0.f}, acc2 = {0.f, 0.f, 0.f, 0.f};
#pragma unroll
    for (int t = 0; t < 12; t++) {
      short8 a0 = *(const short8*)&h_cur[hf[0] * 384 + t * 32 + kg * 8];
      MFMA_AB(acc0, a0, wpc0[t]);
      short8 a1 = *(const short8*)&h_cur[hf[1] * 384 + t * 32 + kg * 8];
      MFMA_AB(acc1, a1, wpc1[t]);
      short8 a2 = *(const short8*)&h_cur[hf[2] * 384 + t * 32 + kg * 8];
      MFMA_AB(acc2, a2, wpc2[t]);
    }
    asm volatile("s_nop 7\n\ts_nop 7");
    if (kg == 0) {
      gacc[(gg[0] * 64 + 16 * qq[0] + c16) * 2 + hf[0]] = acc0[0];
      gacc[(gg[1] * 64 + 16 * qq[1] + c16) * 2 + hf[1]] = acc1[0];
      gacc[(gg[2] * 64 + 16 * qq[2] + c16) * 2 + hf[2]] = acc2[0];
    }
    __syncthreads();
    if (tid < 64) {
      const float s0 = gacc[(0 * 64 + tid) * 2] + gacc[(0 * 64 + tid) * 2 + 1];
      const float s1 = gacc[(1 * 64 + tid) * 2] + gacc[(1 * 64 + tid) * 2 + 1];
      const float s2 = gacc[(2 * 64 + tid) * 2] + gacc[(2 * 64 + tid) * 2 + 1];
      const float rg = sigm(gi0 + bb0 + s0);
      const float zg = sigm(gi1 + bb1 + s1);
      const float ng = tanh_(gi2 + bb2 + rg * s2);
      h_own = (1.f - zg) * ng + zg * h_own;
      const unsigned short hb = f2bf(h_own);
      dechs[(size_t)s * 768 + hrow] = hb;
      const unsigned partner = (unsigned)__shfl_down((int)hb, 1) & 0xFFFFu;
      if ((tid & 1) == 0)
        __hip_atomic_store(&hxD[(s & 1) * 384 + 32 * j + (tid >> 1)],
                           ((unsigned)hb & 0xFFFFu) | (partner << 16),
                           __ATOMIC_RELAXED, __HIP_MEMORY_SCOPE_AGENT);
    }
    __syncthreads();
    if (tid == 0)
      __hip_atomic_fetch_add(&ctrD[s], 1, __ATOMIC_RELEASE, __HIP_MEMORY_SCOPE_AGENT);
  }
}

__global__ void gather_dec(const unsigned short* __restrict__ outputs,
                           const int* __restrict__ breaks,
                           float* __restrict__ din, int L)
{
  const int b = blockIdx.x;
  const int start = b ? breaks[b - 1] : 0;
  const unsigned short* src = outputs + (size_t)start * 768;
  for (int d = threadIdx.x; d < 768; d += blockDim.x)
    din[(size_t)b * 768 + d] = bf2f(src[d]);
}

// C[M,N] f32 = A[M,K] bf16 * B[N,K]^T bf16 (scores = dechs . outputs^T)
__global__ __launch_bounds__(256) void gemm_score(
    const unsigned short* __restrict__ A, const unsigned short* __restrict__ B,
    float* __restrict__ C, int M, int N, int K)
{
  __shared__ __align__(16) short As[128 * 32];
  __shared__ __align__(16) short Bs[128 * 32];
  const int tid = threadIdx.x;
  const int lane = tid & 63, w = tid >> 6;
  const int brow = blockIdx.x * 128, bcol = blockIdx.y * 128;
  const int wrow = (w & 1) * 64, wcol = (w >> 1) * 64;
  const int c16 = lane & 15, kg = lane >> 4;
  f32x4 acc[4][4];
#pragma unroll
  for (int m = 0; m < 4; m++)
#pragma unroll
    for (int n = 0; n < 4; n++) { f32x4 z = {0.f, 0.f, 0.f, 0.f}; acc[m][n] = z; }

  const int lrow = tid >> 1, lk = (tid & 1) * 16;
  const unsigned short* ap = A + (size_t)(brow + lrow) * K + lk;
  const unsigned short* bp = B + (size_t)(bcol + lrow) * K + lk;
  short* asw = &As[lrow * 32 + lk];
  short* bsw = &Bs[lrow * 32 + lk];

  for (int kb = 0; kb < K; kb += 32) {
    short8 a0 = *(const short8*)(ap + kb);
    short8 a1 = *(const short8*)(ap + kb + 8);
    short8 b0 = *(const short8*)(bp + kb);
    short8 b1 = *(const short8*)(bp + kb + 8);
    __syncthreads();
    *(short8*)asw = a0;
    *(short8*)(asw + 8) = a1;
    *(short8*)bsw = b0;
    *(short8*)(bsw + 8) = b1;
    __syncthreads();
    short8 af[4], bf[4];
#pragma unroll
    for (int m = 0; m < 4; m++) af[m] = *(const short8*)&As[(wrow + m * 16 + c16) * 32 + kg * 8];
#pragma unroll
    for (int n = 0; n < 4; n++) bf[n] = *(const short8*)&Bs[(wcol + n * 16 + c16) * 32 + kg * 8];
#pragma unroll
    for (int m = 0; m < 4; m++)
#pragma unroll
      for (int n = 0; n < 4; n++)
        acc[m][n] = __builtin_amdgcn_mfma_f32_16x16x32_bf16(af[m], bf[n], acc[m][n], 0, 0, 0);
  }
#pragma unroll
  for (int n = 0; n < 4; n++) {
    const int col = bcol + wcol + n * 16 + c16;
#pragma unroll
    for (int m = 0; m < 4; m++) {
#pragma unroll
      for (int i = 0; i < 4; i++) {
        const int row = brow + wrow + m * 16 + kg * 4 + i;
        C[(size_t)row * N + col] = acc[m][n][i];
      }
    }
  }
}

// Masked logsumexp over scores[k][start..L) minus score at target.
__global__ __launch_bounds__(256) void loss2(
    const float* __restrict__ scores, const int* __restrict__ breaks,
    float* __restrict__ lossk, int L)
{
  const int k = blockIdx.x;
  const int start = k ? breaks[k - 1] : 0;
  const int target = breaks[k];
  const float* row = scores + (size_t)k * L;
  __shared__ float wm[4], wss[4];
  float m = -3.4e38f, ss = 0.f;
  for (int p = start + threadIdx.x; p < L; p += 256) {
    const float v = row[p];
    if (v > m) { ss = ss * __expf(m - v) + 1.f; m = v; }
    else ss += __expf(v - m);
  }
#pragma unroll
  for (int off = 32; off > 0; off >>= 1) {
    const float mo = __shfl_down(m, off);
    const float so = __shfl_down(ss, off);
    const float mn = fmaxf(m, mo);
    ss = ss * __expf(m - mn) + so * __expf(mo - mn);
    m = mn;
  }
  if ((threadIdx.x & 63) == 0) { wm[threadIdx.x >> 6] = m; wss[threadIdx.x >> 6] = ss; }
  __syncthreads();
  if (threadIdx.x == 0) {
    float M = wm[0], S = wss[0];
#pragma unroll
    for (int q = 1; q < 4; ++q) {
      const float mn = fmaxf(M, wm[q]);
      S = S * __expf(M - mn) + wss[q] * __expf(wm[q] - mn);
      M = mn;
    }
    lossk[k] = (M + __logf(S)) - row[target];
  }
}

__global__ void final_reduce(const float* __restrict__ lossk, float* __restrict__ out, int K)
{
  __shared__ float buf[256];
  float s = 0.f;
  for (int idx = threadIdx.x; idx < K; idx += 256) s += lossk[idx];
  buf[threadIdx.x] = s;
  __syncthreads();
  for (int off = 128; off > 0; off >>= 1) {
    if (threadIdx.x < off) buf[threadIdx.x] += buf[threadIdx.x + off];
    __syncthreads();
  }
  if (threadIdx.x == 0) out[0] = buf[0];
}

extern "C" void kernel_launch(void* const* d_in, const int* in_sizes, int n_in,
                              void* d_out, int out_size, void* d_ws, size_t ws_size,
                              hipStream_t stream)
{
  const float* emb  = (const float*)d_in[0];
  const float* wihF = (const float*)d_in[1];
  const float* whhF = (const float*)d_in[2];
  const float* bihF = (const float*)d_in[3];
  const float* bhhF = (const float*)d_in[4];
  const float* wihB = (const float*)d_in[5];
  const float* whhB = (const float*)d_in[6];
  const float* bihB = (const float*)d_in[7];
  const float* bhhB = (const float*)d_in[8];
  const float* dwih = (const float*)d_in[9];
  const float* dwhh = (const float*)d_in[10];
  const float* dbih = (const float*)d_in[11];
  const float* dbhh = (const float*)d_in[12];
  const int*   brks = (const int*)d_in[13];
  const int L = in_sizes[0] / 768;
  const int K = in_sizes[13];

  auto pad = [](size_t b) { return (b + 255) & ~(size_t)255; };
  const size_t szG   = pad((size_t)L * 1152 * 2);
  const size_t szOut = pad((size_t)L * 768 * 2);
  const size_t szGd  = pad((size_t)K * 2304 * 2);
  const size_t szDin = pad((size_t)K * 768 * 4);
  const size_t szDhs = pad((size_t)K * 768 * 2);
  const size_t szLk  = pad((size_t)K * 4);
  const size_t szHxD = pad(2 * 384 * 4);
  const size_t szHxE = pad(2 * 2 * 96 * 4);          // enc fp8 h slots (1.5 KB)
  const size_t ctrBytes = (2 * (size_t)L + K) * 4;   // ctrE + ctrD contiguous
  const size_t szCtr = pad(ctrBytes);

  char* ws = (char*)d_ws;
  size_t off = 0;
  auto carve = [&](size_t bytes) -> char* { char* p = ws + off; off += bytes; return p; };
  unsigned short* Gf   = (unsigned short*)carve(szG);
  unsigned short* Gb   = (unsigned short*)carve(szG);
  unsigned short* outs = (unsigned short*)carve(szOut);
  unsigned short* Gd   = (unsigned short*)carve(szGd);
  float*          din  = (float*)carve(szDin);
  unsigned short* dhs  = (unsigned short*)carve(szDhs);
  float*          lk   = (float*)carve(szLk);
  unsigned int*   hxD  = (unsigned int*)carve(szHxD);
  unsigned int*   hxE  = (unsigned int*)carve(szHxE);
  int*            ctrE = (int*)carve(szCtr);
  int*            ctrD = ctrE + 2 * (size_t)L;
  float* scores = (float*)Gf;  // alias: Gf dead after enc_scan11; K*L*4 <= szG

  hipMemsetAsync(ctrE, 0, ctrBytes, stream);

  gemm_nt_bias<<<dim3(L / 128, 9), 256, 0, stream>>>(emb, wihF, bihF, Gf, L, 1152, 768);
  gemm_nt_bias<<<dim3(L / 128, 9), 256, 0, stream>>>(emb, wihB, bihB, Gb, L, 1152, 768);
  enc_scan11<<<6, 512, 0, stream>>>(whhF, bhhF, whhB, bhhB, Gf, Gb, outs, hxE, ctrE, L);
  gather_dec<<<K, 256, 0, stream>>>(outs, brks, din, L);
  gemm_nt_bias<<<dim3(K / 128, 18), 256, 0, stream>>>(din, dwih, dbih, Gd, K, 2304, 768);
  dec_scan4<<<12, 512, 0, stream>>>(dwhh, dbhh, Gd, outs, dhs, hxD, ctrD, L, K);
  gemm_score<<<dim3(K / 128, L / 128), 256, 0, stream>>>(dhs, outs, scores, K, L, 768);
  loss2<<<K, 256, 0, stream>>>(scores, brks, lk, L);
  final_reduce<<<1, 256, 0, stream>>>(lk, (float*)d_out, K);
}

// Round 12
// 26172.888 us; speedup vs baseline: 3.6778x; 1.3997x over previous
//
#include <hip/hip_runtime.h>
#include <hip/hip_bf16.h>
#include <stdint.h>

typedef __attribute__((ext_vector_type(8))) short short8;
typedef __attribute__((ext_vector_type(4))) float f32x4;
typedef unsigned long long u64;

__device__ __forceinline__ unsigned short f2bf(float f) {
  union { float f; unsigned u; } v; v.f = f;
  unsigned r = v.u + 0x7FFFu + ((v.u >> 16) & 1u);
  return (unsigned short)(r >> 16);
}
__device__ __forceinline__ float bf2f(unsigned short h) {
  union { unsigned u; float f; } v; v.u = ((unsigned)h) << 16;
  return v.f;
}
__device__ __forceinline__ float sigm(float x) {
  x = fminf(fmaxf(x, -30.f), 30.f);
  return 1.f / (1.f + __expf(-x));
}
__device__ __forceinline__ float tanh_(float x) {
  x = fminf(fmaxf(x, -15.f), 15.f);
  float t = __expf(2.f * x);
  return (t - 1.f) / (t + 1.f);
}
__device__ __forceinline__ short8 pack8(float4 u, float4 v) {
  short8 r;
  r[0] = (short)f2bf(u.x); r[1] = (short)f2bf(u.y); r[2] = (short)f2bf(u.z); r[3] = (short)f2bf(u.w);
  r[4] = (short)f2bf(v.x); r[5] = (short)f2bf(v.y); r[6] = (short)f2bf(v.z); r[7] = (short)f2bf(v.w);
  return r;
}
// Pack 8 f32 (pre-scaled) into 8 e4m3 bytes (one u64).
__device__ __forceinline__ u64 pack_fp8x8(float4 u, float4 v, float scale) {
  int lo = 0, hi = 0;
  lo = __builtin_amdgcn_cvt_pk_fp8_f32(u.x * scale, u.y * scale, lo, false);
  lo = __builtin_amdgcn_cvt_pk_fp8_f32(u.z * scale, u.w * scale, lo, true);
  hi = __builtin_amdgcn_cvt_pk_fp8_f32(v.x * scale, v.y * scale, hi, false);
  hi = __builtin_amdgcn_cvt_pk_fp8_f32(v.z * scale, v.w * scale, hi, true);
  return ((u64)(unsigned)lo) | (((u64)(unsigned)hi) << 32);
}

// bf16 MFMA with B pinned to AGPRs.
#define MFMA_AB(acc, a, b) \
  asm("v_mfma_f32_16x16x32_bf16 %0, %1, %2, %0" : "+v"(acc) : "v"(a), "a"(b))
// fp8 MFMA: acc in VGPR; B from AGPR (persistent weights).
#define MFMA8_WA(acc, a, b) \
  asm("v_mfma_f32_16x16x32_fp8_fp8 %0, %1, %2, %0" : "+v"(acc) : "v"(a), "a"(b))

// Raw barrier (no vmcnt drain) with LDS drain + compiler fences.
#define LDS_BARRIER() do { \
  asm volatile("s_waitcnt lgkmcnt(0)" ::: "memory"); \
  __builtin_amdgcn_s_barrier(); \
  asm volatile("" ::: "memory"); \
} while (0)

// C[M,N] bf16 = A[M,K] f32 * B[N,K]^T f32 + bias[N].  M,N mult of 128, K mult of 32.
__global__ __launch_bounds__(256) void gemm_nt_bias(
    const float* __restrict__ A, const float* __restrict__ B,
    const float* __restrict__ bias, unsigned short* __restrict__ C,
    int M, int N, int K)
{
  __shared__ __align__(16) short As[128 * 32];
  __shared__ __align__(16) short Bs[128 * 32];
  const int tid = threadIdx.x;
  const int lane = tid & 63, w = tid >> 6;
  const int brow = blockIdx.x * 128, bcol = blockIdx.y * 128;
  const int wrow = (w & 1) * 64, wcol = (w >> 1) * 64;
  const int c16 = lane & 15, kg = lane >> 4;
  f32x4 acc[4][4];
#pragma unroll
  for (int m = 0; m < 4; m++)
#pragma unroll
    for (int n = 0; n < 4; n++) { f32x4 z = {0.f, 0.f, 0.f, 0.f}; acc[m][n] = z; }

  const int lrow = tid >> 1, lk = (tid & 1) * 16;
  const float* ap = A + (size_t)(brow + lrow) * K + lk;
  const float* bp = B + (size_t)(bcol + lrow) * K + lk;
  short* asw = &As[lrow * 32 + lk];
  short* bsw = &Bs[lrow * 32 + lk];

  for (int kb = 0; kb < K; kb += 32) {
    float4 a0 = *(const float4*)(ap + kb);
    float4 a1 = *(const float4*)(ap + kb + 4);
    float4 a2 = *(const float4*)(ap + kb + 8);
    float4 a3 = *(const float4*)(ap + kb + 12);
    float4 b0 = *(const float4*)(bp + kb);
    float4 b1 = *(const float4*)(bp + kb + 4);
    float4 b2 = *(const float4*)(bp + kb + 8);
    float4 b3 = *(const float4*)(bp + kb + 12);
    __syncthreads();
    *(short8*)asw = pack8(a0, a1);
    *(short8*)(asw + 8) = pack8(a2, a3);
    *(short8*)bsw = pack8(b0, b1);
    *(short8*)(bsw + 8) = pack8(b2, b3);
    __syncthreads();
    short8 af[4], bf[4];
#pragma unroll
    for (int m = 0; m < 4; m++) af[m] = *(const short8*)&As[(wrow + m * 16 + c16) * 32 + kg * 8];
#pragma unroll
    for (int n = 0; n < 4; n++) bf[n] = *(const short8*)&Bs[(wcol + n * 16 + c16) * 32 + kg * 8];
#pragma unroll
    for (int m = 0; m < 4; m++)
#pragma unroll
      for (int n = 0; n < 4; n++)
        acc[m][n] = __builtin_amdgcn_mfma_f32_16x16x32_bf16(af[m], bf[n], acc[m][n], 0, 0, 0);
  }
#pragma unroll
  for (int n = 0; n < 4; n++) {
    const int col = bcol + wcol + n * 16 + c16;
    const float bv = bias[col];
#pragma unroll
    for (int m = 0; m < 4; m++) {
#pragma unroll
      for (int i = 0; i < 4; i++) {
        const int row = brow + wrow + m * 16 + kg * 4 + i;
        C[(size_t)row * N + col] = f2bf(acc[m][n][i] + bv);
      }
    }
  }
}

// Encoder GRU scan, fp8 weights, 3 WGs x 8 waves per direction (r11 compute,
// proven). Cross-WG h exchange via TAGGED SLOTS: one u64 atomic word =
// {tag=si+1 (hi32), 4 fp8 h-rows (lo32)} — tag rides with data, so no vmcnt
// drain, no flag counter, ~1.5 coherence RTTs instead of 4.
// Deadlock-safety (r9/r10 root cause was intra-wave publish/poll divergence):
// publishers are WAVE 0, pollers are WAVE 1 — disjoint waves, separate ifs.
// A poller depends only on REMOTE WGs' wave-0 publish, which runs
// unconditionally after that WG's first barrier => no circular wait.
// Ring-2 reuse safe: publishing tag t+2 into a slot requires having consumed
// t+1, which peers published only after consuming t from that slot.
__global__ __launch_bounds__(512) __attribute__((amdgpu_waves_per_eu(2, 2)))
void enc_scan12(
    const float* __restrict__ WhhF, const float* __restrict__ bhhF,
    const float* __restrict__ WhhB, const float* __restrict__ bhhB,
    const unsigned short* __restrict__ Gf, const unsigned short* __restrict__ Gb,
    unsigned short* __restrict__ outputs, u64* __restrict__ slots, int L)
{
  const int dir = blockIdx.x & 1;
  const int r = blockIdx.x >> 1;  // 0..2
  const float* Whh = dir ? WhhB : WhhF;
  const float* bhh = dir ? bhhB : bhhF;
  const unsigned short* G = dir ? Gb : Gf;
  u64* dslots = slots + (size_t)dir * 2 * 3 * 32;  // [ring2][wg3][32]

  const int tid = threadIdx.x, lane = tid & 63, w = tid >> 6;
  const int c16 = lane & 15, kg = lane >> 4;

  __shared__ __align__(8) u64 h_qd[96];  // [ring2][48] u64 = 2 x 384 fp8 bytes
  unsigned char* h8 = (unsigned char*)h_qd;

  // ---- Prologue: quantize this wave's weights into 72 AGPRs ----
  const int myrow = 128 * r + 16 * w + c16;
  u64 wq[3][12];
  float bb[3];
#pragma unroll
  for (int g = 0; g < 3; g++) {
    const int jrow = g * 384 + myrow;
    bb[g] = bhh[jrow];
    const float* rp = Whh + (size_t)jrow * 384 + kg * 8;
#pragma unroll
    for (int t = 0; t < 12; t++) {
      float4 x0 = *(const float4*)(rp + t * 32);
      float4 x1 = *(const float4*)(rp + t * 32 + 4);
      wq[g][t] = pack_fp8x8(x0, x1, 256.f);
    }
  }
  float h_own = 0.f;  // kg-redundant state for row myrow
  unsigned short gr0, gr1, gr2;
  {
    const int s0 = dir ? (L - 1) : 0;
    const size_t gb = (size_t)s0 * 1152 + myrow;
    gr0 = G[gb]; gr1 = G[gb + 384]; gr2 = G[gb + 768];
  }
  if (tid < 48) h_qd[tid] = 0ull;  // h8[ring 0] = 0
  __syncthreads();

  const float INV = 1.f / 16384.f;
  for (int si = 0; si < L; ++si) {
    const int s = dir ? (L - 1 - si) : si;
    const int cur = si & 1, nxt = cur ^ 1;

    // ---- MFMA: 3 gate-tiles x 12 K-chunks (B in AGPR) ----
    f32x4 a0 = {0.f, 0.f, 0.f, 0.f}, a1 = {0.f, 0.f, 0.f, 0.f}, a2 = {0.f, 0.f, 0.f, 0.f};
#pragma unroll
    for (int t = 0; t < 12; t++) {
      const u64 a = h_qd[cur * 48 + 4 * t + kg];
      MFMA8_WA(a0, a, wq[0][t]);
      MFMA8_WA(a1, a, wq[1][t]);
      MFMA8_WA(a2, a, wq[2][t]);
    }
    asm volatile("s_nop 7\n\ts_nop 7");

    // ---- combine (kg-redundant) ----
    const float rg = sigm(bf2f(gr0) + bb[0] + a0[0] * INV);
    const float zg = sigm(bf2f(gr1) + bb[1] + a1[0] * INV);
    const float ng = tanh_(bf2f(gr2) + rg * (a2[0] * INV + bb[2]));
    h_own = (1.f - zg) * ng + zg * h_own;
    if (kg == 0) {
      outputs[(size_t)s * 768 + dir * 384 + myrow] = f2bf(h_own);
      const int pk = __builtin_amdgcn_cvt_pk_fp8_f32(h_own * 64.f, h_own * 64.f, 0, false);
      h8[nxt * 384 + myrow] = (unsigned char)(pk & 0xFF);
    }
    // prefetch next-step gi (stays in flight across lgkm-only barriers)
    if (si + 1 < L) {
      const int sn = dir ? (L - 2 - si) : (si + 1);
      const size_t gb = (size_t)sn * 1152 + myrow;
      gr0 = G[gb]; gr1 = G[gb + 384]; gr2 = G[gb + 768];
    }

    if (si + 1 < L) {
      LDS_BARRIER();  // h8[nxt] own-strip bytes visible; h_qd[cur] reads done
      const unsigned tag = (unsigned)(si + 1);
      if (w == 0) {
        // WAVE 0: publish our 128-row strip as 32 tagged words
        if (lane < 32) {
          const unsigned d = *(const unsigned*)&h8[nxt * 384 + 128 * r + 4 * lane];
          __hip_atomic_store(&dslots[(nxt * 3 + r) * 32 + lane],
                             ((u64)tag << 32) | d,
                             __ATOMIC_RELAXED, __HIP_MEMORY_SCOPE_AGENT);
        }
      }
      if (w == 1) {
        // WAVE 1: poll the 64 remote words; deposit into LDS
        const int wgR = (lane < 32) ? ((r + 1) % 3) : ((r + 2) % 3);
        const int k = lane & 31;
        u64* sp = &dslots[(nxt * 3 + wgR) * 32 + k];
        u64 v = __hip_atomic_load(sp, __ATOMIC_RELAXED, __HIP_MEMORY_SCOPE_AGENT);
        while ((unsigned)(v >> 32) < tag)
          v = __hip_atomic_load(sp, __ATOMIC_RELAXED, __HIP_MEMORY_SCOPE_AGENT);
        *(unsigned*)&h8[nxt * 384 + 128 * wgR + 4 * k] = (unsigned)v;
      }
      LDS_BARRIER();  // h8[nxt] complete for next step
    }
  }
}

// Decoder GRU scan: 12 WGs x 8 waves, bf16 weights in AGPR (proven in r4-r11).
__global__ __launch_bounds__(512) __attribute__((amdgpu_waves_per_eu(2, 2)))
void dec_scan4(
    const float* __restrict__ Whh, const float* __restrict__ bhh,
    const unsigned short* __restrict__ Gd, const unsigned short* __restrict__ outputs,
    unsigned short* __restrict__ dechs, unsigned int* __restrict__ hxD,
    int* __restrict__ ctrD, int L, int Ksteps)
{
  const int j = blockIdx.x;  // 0..11
  const int tid = threadIdx.x, lane = tid & 63, w = tid >> 6;
  const int c16 = lane & 15, kg = lane >> 4;

  __shared__ __align__(16) unsigned short h_cur[768];
  __shared__ float gacc[3 * 64 * 2];

  int hf[3], gg[3], qq[3];
  short8 wpc0[12], wpc1[12], wpc2[12];
#pragma unroll
  for (int e = 0; e < 3; e++) {
    const int p = 3 * w + e;
    hf[e] = p & 1;
    gg[e] = (p >> 1) >> 2;
    qq[e] = (p >> 1) & 3;
  }
  {
    const float* rp0 = Whh + (size_t)(gg[0] * 768 + 64 * j + 16 * qq[0] + c16) * 768 + hf[0] * 384 + kg * 8;
    const float* rp1 = Whh + (size_t)(gg[1] * 768 + 64 * j + 16 * qq[1] + c16) * 768 + hf[1] * 384 + kg * 8;
    const float* rp2 = Whh + (size_t)(gg[2] * 768 + 64 * j + 16 * qq[2] + c16) * 768 + hf[2] * 384 + kg * 8;
#pragma unroll
    for (int t = 0; t < 12; t++) {
      wpc0[t] = pack8(*(const float4*)(rp0 + t * 32), *(const float4*)(rp0 + t * 32 + 4));
      wpc1[t] = pack8(*(const float4*)(rp1 + t * 32), *(const float4*)(rp1 + t * 32 + 4));
      wpc2[t] = pack8(*(const float4*)(rp2 + t * 32), *(const float4*)(rp2 + t * 32 + 4));
    }
  }
  const unsigned short* outLast = outputs + (size_t)(L - 1) * 768;
  const int hrow = 64 * j + tid;  // combine row (tid<64)
  float bb0 = 0.f, bb1 = 0.f, bb2 = 0.f, h_own = 0.f;
  if (tid < 64) {
    bb0 = bhh[hrow]; bb1 = bhh[768 + hrow]; bb2 = bhh[1536 + hrow];
    h_own = bf2f(outLast[hrow]);
  }
  if (tid < 384) ((unsigned*)h_cur)[tid] = ((const unsigned*)outLast)[tid];
  __syncthreads();

  for (int s = 0; s < Ksteps; ++s) {
    float gi0 = 0.f, gi1 = 0.f, gi2 = 0.f;
    if (tid < 64) {
      const size_t gb = (size_t)s * 2304 + hrow;
      gi0 = bf2f(Gd[gb]); gi1 = bf2f(Gd[gb + 768]); gi2 = bf2f(Gd[gb + 1536]);
    }
    if (s > 0) {
      if (tid == 0)
        while (__hip_atomic_load(&ctrD[s - 1], __ATOMIC_ACQUIRE, __HIP_MEMORY_SCOPE_AGENT) < 12)
          __builtin_amdgcn_s_sleep(1);
      __syncthreads();
      if (tid < 384) {
        unsigned v = __hip_atomic_load(&hxD[((s - 1) & 1) * 384 + tid],
                                       __ATOMIC_RELAXED, __HIP_MEMORY_SCOPE_AGENT);
        ((unsigned*)h_cur)[tid] = v;
      }
      __syncthreads();
    }
    f32x4 acc0 = {0.f, 0.f, 0.f, 0.f}, acc1 = {0.f, 0.f, 0.f, 0.f}, acc2 = {0.f, 0.f, 0.f, 0.f};
#pragma unroll
    for (int t = 0; t < 12; t++) {
      short8 a0 = *(const short8*)&h_cur[hf[0] * 384 + t * 32 + kg * 8];
      MFMA_AB(acc0, a0, wpc0[t]);
      short8 a1 = *(const short8*)&h_cur[hf[1] * 384 + t * 32 + kg * 8];
      MFMA_AB(acc1, a1, wpc1[t]);
      short8 a2 = *(const short8*)&h_cur[hf[2] * 384 + t * 32 + kg * 8];
      MFMA_AB(acc2, a2, wpc2[t]);
    }
    asm volatile("s_nop 7\n\ts_nop 7");
    if (kg == 0) {
      gacc[(gg[0] * 64 + 16 * qq[0] + c16) * 2 + hf[0]] = acc0[0];
      gacc[(gg[1] * 64 + 16 * qq[1] + c16) * 2 + hf[1]] = acc1[0];
      gacc[(gg[2] * 64 + 16 * qq[2] + c16) * 2 + hf[2]] = acc2[0];
    }
    __syncthreads();
    if (tid < 64) {
      const float s0 = gacc[(0 * 64 + tid) * 2] + gacc[(0 * 64 + tid) * 2 + 1];
      const float s1 = gacc[(1 * 64 + tid) * 2] + gacc[(1 * 64 + tid) * 2 + 1];
      const float s2 = gacc[(2 * 64 + tid) * 2] + gacc[(2 * 64 + tid) * 2 + 1];
      const float rg = sigm(gi0 + bb0 + s0);
      const float zg = sigm(gi1 + bb1 + s1);
      const float ng = tanh_(gi2 + bb2 + rg * s2);
      h_own = (1.f - zg) * ng + zg * h_own;
      const unsigned short hb = f2bf(h_own);
      dechs[(size_t)s * 768 + hrow] = hb;
      const unsigned partner = (unsigned)__shfl_down((int)hb, 1) & 0xFFFFu;
      if ((tid & 1) == 0)
        __hip_atomic_store(&hxD[(s & 1) * 384 + 32 * j + (tid >> 1)],
                           ((unsigned)hb & 0xFFFFu) | (partner << 16),
                           __ATOMIC_RELAXED, __HIP_MEMORY_SCOPE_AGENT);
    }
    __syncthreads();
    if (tid == 0)
      __hip_atomic_fetch_add(&ctrD[s], 1, __ATOMIC_RELEASE, __HIP_MEMORY_SCOPE_AGENT);
  }
}

__global__ void gather_dec(const unsigned short* __restrict__ outputs,
                           const int* __restrict__ breaks,
                           float* __restrict__ din, int L)
{
  const int b = blockIdx.x;
  const int start = b ? breaks[b - 1] : 0;
  const unsigned short* src = outputs + (size_t)start * 768;
  for (int d = threadIdx.x; d < 768; d += blockDim.x)
    din[(size_t)b * 768 + d] = bf2f(src[d]);
}

// C[M,N] f32 = A[M,K] bf16 * B[N,K]^T bf16 (scores = dechs . outputs^T)
__global__ __launch_bounds__(256) void gemm_score(
    const unsigned short* __restrict__ A, const unsigned short* __restrict__ B,
    float* __restrict__ C, int M, int N, int K)
{
  __shared__ __align__(16) short As[128 * 32];
  __shared__ __align__(16) short Bs[128 * 32];
  const int tid = threadIdx.x;
  const int lane = tid & 63, w = tid >> 6;
  const int brow = blockIdx.x * 128, bcol = blockIdx.y * 128;
  const int wrow = (w & 1) * 64, wcol = (w >> 1) * 64;
  const int c16 = lane & 15, kg = lane >> 4;
  f32x4 acc[4][4];
#pragma unroll
  for (int m = 0; m < 4; m++)
#pragma unroll
    for (int n = 0; n < 4; n++) { f32x4 z = {0.f, 0.f, 0.f, 0.f}; acc[m][n] = z; }

  const int lrow = tid >> 1, lk = (tid & 1) * 16;
  const unsigned short* ap = A + (size_t)(brow + lrow) * K + lk;
  const unsigned short* bp = B + (size_t)(bcol + lrow) * K + lk;
  short* asw = &As[lrow * 32 + lk];
  short* bsw = &Bs[lrow * 32 + lk];

  for (int kb = 0; kb < K; kb += 32) {
    short8 a0 = *(const short8*)(ap + kb);
    short8 a1 = *(const short8*)(ap + kb + 8);
    short8 b0 = *(const short8*)(bp + kb);
    short8 b1 = *(const short8*)(bp + kb + 8);
    __syncthreads();
    *(short8*)asw = a0;
    *(short8*)(asw + 8) = a1;
    *(short8*)bsw = b0;
    *(short8*)(bsw + 8) = b1;
    __syncthreads();
    short8 af[4], bf[4];
#pragma unroll
    for (int m = 0; m < 4; m++) af[m] = *(const short8*)&As[(wrow + m * 16 + c16) * 32 + kg * 8];
#pragma unroll
    for (int n = 0; n < 4; n++) bf[n] = *(const short8*)&Bs[(wcol + n * 16 + c16) * 32 + kg * 8];
#pragma unroll
    for (int m = 0; m < 4; m++)
#pragma unroll
      for (int n = 0; n < 4; n++)
        acc[m][n] = __builtin_amdgcn_mfma_f32_16x16x32_bf16(af[m], bf[n], acc[m][n], 0, 0, 0);
  }
#pragma unroll
  for (int n = 0; n < 4; n++) {
    const int col = bcol + wcol + n * 16 + c16;
#pragma unroll
    for (int m = 0; m < 4; m++) {
#pragma unroll
      for (int i = 0; i < 4; i++) {
        const int row = brow + wrow + m * 16 + kg * 4 + i;
        C[(size_t)row * N + col] = acc[m][n][i];
      }
    }
  }
}

// Masked logsumexp over scores[k][start..L) minus score at target.
__global__ __launch_bounds__(256) void loss2(
    const float* __restrict__ scores, const int* __restrict__ breaks,
    float* __restrict__ lossk, int L)
{
  const int k = blockIdx.x;
  const int start = k ? breaks[k - 1] : 0;
  const int target = breaks[k];
  const float* row = scores + (size_t)k * L;
  __shared__ float wm[4], wss[4];
  float m = -3.4e38f, ss = 0.f;
  for (int p = start + threadIdx.x; p < L; p += 256) {
    const float v = row[p];
    if (v > m) { ss = ss * __expf(m - v) + 1.f; m = v; }
    else ss += __expf(v - m);
  }
#pragma unroll
  for (int off = 32; off > 0; off >>= 1) {
    const float mo = __shfl_down(m, off);
    const float so = __shfl_down(ss, off);
    const float mn = fmaxf(m, mo);
    ss = ss * __expf(m - mn) + so * __expf(mo - mn);
    m = mn;
  }
  if ((threadIdx.x & 63) == 0) { wm[threadIdx.x >> 6] = m; wss[threadIdx.x >> 6] = ss; }
  __syncthreads();
  if (threadIdx.x == 0) {
    float M = wm[0], S = wss[0];
#pragma unroll
    for (int q = 1; q < 4; ++q) {
      const float mn = fmaxf(M, wm[q]);
      S = S * __expf(M - mn) + wss[q] * __expf(wm[q] - mn);
      M = mn;
    }
    lossk[k] = (M + __logf(S)) - row[target];
  }
}

__global__ void final_reduce(const float* __restrict__ lossk, float* __restrict__ out, int K)
{
  __shared__ float buf[256];
  float s = 0.f;
  for (int idx = threadIdx.x; idx < K; idx += 256) s += lossk[idx];
  buf[threadIdx.x] = s;
  __syncthreads();
  for (int off = 128; off > 0; off >>= 1) {
    if (threadIdx.x < off) buf[threadIdx.x] += buf[threadIdx.x + off];
    __syncthreads();
  }
  if (threadIdx.x == 0) out[0] = buf[0];
}

extern "C" void kernel_launch(void* const* d_in, const int* in_sizes, int n_in,
                              void* d_out, int out_size, void* d_ws, size_t ws_size,
                              hipStream_t stream)
{
  const float* emb  = (const float*)d_in[0];
  const float* wihF = (const float*)d_in[1];
  const float* whhF = (const float*)d_in[2];
  const float* bihF = (const float*)d_in[3];
  const float* bhhF = (const float*)d_in[4];
  const float* wihB = (const float*)d_in[5];
  const float* whhB = (const float*)d_in[6];
  const float* bihB = (const float*)d_in[7];
  const float* bhhB = (const float*)d_in[8];
  const float* dwih = (const float*)d_in[9];
  const float* dwhh = (const float*)d_in[10];
  const float* dbih = (const float*)d_in[11];
  const float* dbhh = (const float*)d_in[12];
  const int*   brks = (const int*)d_in[13];
  const int L = in_sizes[0] / 768;
  const int K = in_sizes[13];

  auto pad = [](size_t b) { return (b + 255) & ~(size_t)255; };
  const size_t szG    = pad((size_t)L * 1152 * 2);
  const size_t szOut  = pad((size_t)L * 768 * 2);
  const size_t szGd   = pad((size_t)K * 2304 * 2);
  const size_t szDin  = pad((size_t)K * 768 * 4);
  const size_t szDhs  = pad((size_t)K * 768 * 2);
  const size_t szLk   = pad((size_t)K * 4);
  const size_t szHxD  = pad(2 * 384 * 4);
  const size_t szSlot = pad(2 * 2 * 3 * 32 * 8);  // enc tagged slots (3 KB)
  const size_t szCtr  = pad((size_t)K * 4);       // ctrD only

  char* ws = (char*)d_ws;
  size_t off = 0;
  auto carve = [&](size_t bytes) -> char* { char* p = ws + off; off += bytes; return p; };
  unsigned short* Gf    = (unsigned short*)carve(szG);
  unsigned short* Gb    = (unsigned short*)carve(szG);
  unsigned short* outs  = (unsigned short*)carve(szOut);
  unsigned short* Gd    = (unsigned short*)carve(szGd);
  float*          din   = (float*)carve(szDin);
  unsigned short* dhs   = (unsigned short*)carve(szDhs);
  float*          lk    = (float*)carve(szLk);
  unsigned int*   hxD   = (unsigned int*)carve(szHxD);
  u64*            slots = (u64*)carve(szSlot);
  int*            ctrD  = (int*)carve(szCtr);
  float* scores = (float*)Gf;  // alias: Gf dead after enc_scan12; K*L*4 <= szG

  // zero slots + ctrD in one contiguous memset (they are adjacent carves)
  hipMemsetAsync(slots, 0, szSlot + szCtr, stream);

  gemm_nt_bias<<<dim3(L / 128, 9), 256, 0, stream>>>(emb, wihF, bihF, Gf, L, 1152, 768);
  gemm_nt_bias<<<dim3(L / 128, 9), 256, 0, stream>>>(emb, wihB, bihB, Gb, L, 1152, 768);
  enc_scan12<<<6, 512, 0, stream>>>(whhF, bhhF, whhB, bhhB, Gf, Gb, outs, slots, L);
  gather_dec<<<K, 256, 0, stream>>>(outs, brks, din, L);
  gemm_nt_bias<<<dim3(K / 128, 18), 256, 0, stream>>>(din, dwih, dbih, Gd, K, 2304, 768);
  dec_scan4<<<12, 512, 0, stream>>>(dwhh, dbhh, Gd, outs, dhs, hxD, ctrD, L, K);
  gemm_score<<<dim3(K / 128, L / 128), 256, 0, stream>>>(dhs, outs, scores, K, L, 768);
  loss2<<<K, 256, 0, stream>>>(scores, brks, lk, L);
  final_reduce<<<1, 256, 0, stream>>>(lk, (float*)d_out, K);
}